// Round 4
// baseline (778.932 us; speedup 1.0000x reference)
//
#include <hip/hip_runtime.h>
#include <hip/hip_bf16.h>

#define NA 20000
#define NP 50000
#define NE 300000
#define DD 256
#define HH 8
#define NTOT (2 * NP + NA)           // 120000 joint dst buckets
#define NBLK ((NTOT + 2047) / 2048)  // 59 scan blocks

typedef short bf16x8 __attribute__((ext_vector_type(8)));
typedef float f32x4 __attribute__((ext_vector_type(4)));

__device__ __forceinline__ float b2f(ushort u) {
  unsigned v = ((unsigned)u) << 16;
  float f;
  __builtin_memcpy(&f, &v, 4);
  return f;
}
__device__ __forceinline__ float b2f_lo(int u) {
  unsigned v = ((unsigned)u) << 16;
  float f;
  __builtin_memcpy(&f, &v, 4);
  return f;
}
__device__ __forceinline__ float b2f_hi(int u) {
  unsigned v = ((unsigned)u) & 0xffff0000u;
  float f;
  __builtin_memcpy(&f, &v, 4);
  return f;
}
__device__ __forceinline__ ushort f2b(float f) {
  unsigned u;
  __builtin_memcpy(&u, &f, 4);
  u = u + 0x7fffu + ((u >> 16) & 1u);
  return (ushort)(u >> 16);
}
__device__ __forceinline__ unsigned pk2(float lo, float hi) {
  return (unsigned)f2b(lo) | ((unsigned)f2b(hi) << 16);
}
// dual-dtype scalar load / store (isbf: 1 = bf16, 0 = fp32)
__device__ __forceinline__ float ldf(const void* p, int i, int isbf) {
  return isbf ? b2f(((const ushort*)p)[i]) : ((const float*)p)[i];
}
__device__ __forceinline__ void stf(void* p, size_t i, float v, int isbf) {
  if (isbf) ((ushort*)p)[i] = f2b(v);
  else ((float*)p)[i] = v;
}
// async global->LDS, 16B per lane; LDS dest must be wave-uniform base (+lane*16 implicit)
__device__ __forceinline__ void gload16(const void* g, void* l) {
  __builtin_amdgcn_global_load_lds(
      (const __attribute__((address_space(1))) void*)g,
      (__attribute__((address_space(3))) void*)l, 16, 0, 0);
}

// rel_pri is all-ones: first u32 is 0x3F803F80 if bf16-packed, 0x3F800000 if fp32.
__global__ void detect_dtype(const unsigned* __restrict__ pri, int* __restrict__ dtf) {
  if (threadIdx.x == 0) *dtf = (pri[0] == 0x3F803F80u) ? 1 : 0;
}

// convert h_a / h_p to bf16 tables once (8 elems/thread)
__global__ __launch_bounds__(256) void cvt_h(const void* __restrict__ ha,
                                             const void* __restrict__ hp,
                                             ushort* __restrict__ Ha,
                                             ushort* __restrict__ Hp,
                                             const int* __restrict__ dtf) {
  int isbf = *dtf;
  size_t t = (size_t)blockIdx.x * 256 + threadIdx.x;
  const size_t nA = (size_t)NA * 256 / 8;        // 640000
  const size_t nT = nA + (size_t)NP * 256 / 8;   // 2240000
  if (t >= nT) return;
  const void* src;
  ushort* dst;
  size_t o;
  if (t < nA) { src = ha; dst = Ha; o = t * 8; }
  else        { src = hp; dst = Hp; o = (t - nA) * 8; }
  if (isbf) {
    *(int4*)(dst + o) = *(const int4*)((const ushort*)src + o);
  } else {
    const float* f = (const float*)src + o;
    float4 x = *(const float4*)f;
    float4 y = *(const float4*)(f + 4);
    int4 v;
    v.x = (int)pk2(x.x, x.y); v.y = (int)pk2(x.z, x.w);
    v.z = (int)pk2(y.x, y.y); v.w = (int)pk2(y.z, y.w);
    *(int4*)(dst + o) = v;
  }
}

// fused: y<3 -> Qeff rows into B panels; y>=3 -> Aeff
// Bp rows: [0,256)=kw1 [256,512)=vw1 [512,768)=qeff e0 [768,1024)=qeff e1
// Ba rows: [0,256)=kw0 [256,512)=vw0 [512,768)=qeff e2
__global__ __launch_bounds__(256) void build_eff(const void* __restrict__ q_w,
                                                 const void* __restrict__ a_w,
                                                 const void* __restrict__ ratt,
                                                 const void* __restrict__ rmsg,
                                                 ushort* __restrict__ Bp,
                                                 ushort* __restrict__ Ba,
                                                 ushort* __restrict__ aeff,
                                                 const int* __restrict__ dtf) {
  int isbf = *dtf;
  int y = blockIdx.y;
  int r = blockIdx.x;
  int c = threadIdx.x;
  if (y < 3) {
    int e = y;
    int nt = (e == 2) ? 0 : 1;
    int h = r >> 5, i = r & 31;
    int rb = ((e * HH + h) * 32 + i) * 32;
    int qb = nt * 65536 + (h * 32) * 256 + c;
    float s = 0.f;
#pragma unroll 8
    for (int j = 0; j < 32; j++) s += ldf(ratt, rb + j, isbf) * ldf(q_w, qb + j * 256, isbf);
    ushort* dst = (e == 2) ? (Ba + (size_t)(512 + r) * 256)
                           : (Bp + (size_t)(512 + e * 256 + r) * 256);
    dst[c] = f2b(s);
  } else {
    int e = y - 3;
    int o = r;
    int nt = (e == 2) ? 0 : 1;
    int h = c >> 5, i = c & 31;
    int rb = ((e * HH + h) * 32 + i) * 32;
    int ab = nt * 65536 + o * 256 + h * 32;
    float s = 0.f;
#pragma unroll 8
    for (int j = 0; j < 32; j++) s += ldf(rmsg, rb + j, isbf) * ldf(a_w, ab + j, isbf);
    aeff[(e * 256 + o) * 256 + c] = f2b(s);
  }
}

// convert external k_w/v_w into the bf16 B panels (4 sections x 65536 elems, 8/thread)
__global__ __launch_bounds__(256) void cvt_wt(const void* __restrict__ kw,
                                              const void* __restrict__ vw,
                                              ushort* __restrict__ Bp,
                                              ushort* __restrict__ Ba,
                                              const int* __restrict__ dtf) {
  int isbf = *dtf;
  int t = blockIdx.x * 256 + threadIdx.x;  // 0..32767
  int sec = t >> 13;
  int o = (t & 8191) * 8;
  const void* src = (sec == 0 || sec == 2) ? kw : vw;
  size_t soff = (sec < 2) ? (size_t)(65536 + o) : (size_t)o;
  ushort* dst = (sec == 0) ? (Bp + o)
              : (sec == 1) ? (Bp + 65536 + o)
              : (sec == 2) ? (Ba + o)
                           : (Ba + 65536 + o);
  if (isbf) {
    *(int4*)dst = *(const int4*)((const ushort*)src + soff);
  } else {
    const float* f = (const float*)src + soff;
    float4 x = *(const float4*)f;
    float4 y = *(const float4*)(f + 4);
    int4 v;
    v.x = (int)pk2(x.x, x.y); v.y = (int)pk2(x.z, x.w);
    v.z = (int)pk2(y.x, y.y); v.w = (int)pk2(y.z, y.w);
    *(int4*)dst = v;
  }
}

// gb layout (fp32): [0]=kb1 [1]=vb1 [2]=qeb0 [3]=qeb1 | [4]=kb0 [5]=vb0 [6]=qeb2
__global__ __launch_bounds__(256) void make_biases(const void* __restrict__ k_b,
                                                   const void* __restrict__ v_b,
                                                   const void* __restrict__ q_b,
                                                   const void* __restrict__ ratt,
                                                   float* __restrict__ gb,
                                                   const int* __restrict__ dtf) {
  int isbf = *dtf;
  int c = threadIdx.x;
  gb[0 * 256 + c] = ldf(k_b, 256 + c, isbf);
  gb[1 * 256 + c] = ldf(v_b, 256 + c, isbf);
  gb[4 * 256 + c] = ldf(k_b, c, isbf);
  gb[5 * 256 + c] = ldf(v_b, c, isbf);
  int h = c >> 5, i = c & 31;
  for (int e = 0; e < 3; e++) {
    int ntp = (e == 2) ? 0 : 1;
    int rb = ((e * HH + h) * 32 + i) * 32;
    float s = 0.f;
    for (int j = 0; j < 32; j++)
      s += ldf(ratt, rb + j, isbf) * ldf(q_b, ntp * 256 + h * 32 + j, isbf);
    gb[(e == 2 ? 6 : (2 + e)) * 256 + c] = s;
  }
}

// ---------------- B-resident persistent-row MFMA GEMM ----------------
// 14 jobs via blockIdx.y: y<8 -> NP family (A=Hp, B=Bp panel col0=y*128),
//                         y>=8 -> NA family (A=Ha, B=Ba panel col0=(y-8)*128).
// Each block: stage 64KB B panel (swizzled) once, then 8 row-tiles x 8 K-steps
// with double-buffered A via global_load_lds.
// ilv: 0 = plain [row][256]; 1 = K-half of interleaved KV[row][512]; 2 = V-half.
struct GemmC4 { ushort* c[4]; int ilv[4]; };

__global__ __launch_bounds__(256) void gemm_proj(const ushort* __restrict__ Hp,
                                                 const ushort* __restrict__ Ha,
                                                 const ushort* __restrict__ Bpp,
                                                 const ushort* __restrict__ Bap,
                                                 const float* __restrict__ gb,
                                                 GemmC4 cpp, GemmC4 cpa) {
  const int y = blockIdx.y;
  const int isNP = (y < 8);
  const ushort* A = isNP ? Hp : Ha;
  const ushort* B = isNP ? Bpp : Bap;
  const float* gbias = isNP ? gb : (gb + 1024);
  const int M = isNP ? NP : NA;
  const int col0 = (isNP ? y : (y - 8)) * 128;
  const GemmC4 cp = isNP ? cpp : cpa;
  ushort* C = cp.c[col0 >> 8];
  const int ilv = cp.ilv[col0 >> 8];
  const int ccol0 = col0 & 255;
  const int rowbase = blockIdx.x * 1024;  // 8 row-tiles x 128
  if (rowbase >= M) return;

  __shared__ __align__(16) ushort Bres[32768];  // 64 KB: 128 cols x 256 K, swizzled
  __shared__ __align__(16) ushort As[2][4096];  // 2 x [128][32]

  const int tid = threadIdx.x;
  const int ln = tid & 63;
  const int quad = ln >> 4, lr = ln & 15;
  const int wv = tid >> 6;
  const int wr = wv >> 1, wc = wv & 1;  // 2x2 wave grid over 128x128

  // ---- stage B panel once (linear LDS dest, inverse-swizzled global source) ----
  // target read layout: byte = col*512 + kb*64 + quad*16, XOR ((col&7)<<4)
  {
    const char* Bg = (const char*)(B + (size_t)col0 * 256);
    char* Bl = (char*)Bres;
#pragma unroll
    for (int c = 0; c < 16; c++) {
      int d = c * 4096 + tid * 16;                       // linear dest byte
      int srcb = (d & ~511) | ((d & 511) ^ (((d >> 9) & 7) << 4));
      gload16(Bg + srcb, Bl + c * 4096 + (tid & 192) * 16);
    }
  }

  f32x4 acc[4][4];
#pragma unroll
  for (int m = 0; m < 4; m++)
#pragma unroll
    for (int n = 0; n < 4; n++) acc[m][n] = (f32x4){0.f, 0.f, 0.f, 0.f};

  const int seg = tid & 3, rA = tid >> 2;
  auto stageA = [&](int s, int buf) {
    int rt = s >> 3, kb = s & 7;
    int row0 = rowbase + rt * 128;
    int ar0 = row0 + rA;      if (ar0 >= M) ar0 = M - 1;
    int ar1 = row0 + 64 + rA; if (ar1 >= M) ar1 = M - 1;
    gload16(A + (size_t)ar0 * 256 + seg * 8 + kb * 32, As[buf] + (tid & 192) * 8);
    gload16(A + (size_t)ar1 * 256 + seg * 8 + kb * 32, As[buf] + 2048 + (tid & 192) * 8);
  };

  stageA(0, 0);
  __syncthreads();  // B panel + first A tile resident

  const int voff = (ilv == 2) ? 4 : 0;
  for (int s = 0; s < 64; s++) {
    const int rt = s >> 3, kb = s & 7, cur = s & 1;
    if (s + 1 < 64) stageA(s + 1, cur ^ 1);
    bf16x8 af[4], bfr[4];
#pragma unroll
    for (int m = 0; m < 4; m++)
      af[m] = *(const bf16x8*)&As[cur][(wr * 64 + m * 16 + lr) * 32 + quad * 8];
#pragma unroll
    for (int n = 0; n < 4; n++) {
      int coln = wc * 64 + n * 16 + lr;
      int bb = (coln * 512 + kb * 64 + quad * 16) ^ ((coln & 7) << 4);
      bfr[n] = *(const bf16x8*)((const char*)Bres + bb);
    }
#pragma unroll
    for (int m = 0; m < 4; m++)
#pragma unroll
      for (int n = 0; n < 4; n++)
        acc[m][n] = __builtin_amdgcn_mfma_f32_16x16x32_bf16(af[m], bfr[n], acc[m][n], 0, 0, 0);
    if (kb == 7) {
      // epilogue for row-tile rt, then reset acc
      int row0 = rowbase + rt * 128;
#pragma unroll
      for (int m = 0; m < 4; m++) {
        int rbase = row0 + wr * 64 + m * 16 + quad * 4;
#pragma unroll
        for (int n = 0; n < 4; n++) {
          int ccol = ccol0 + wc * 64 + n * 16 + lr;
          float bv = gbias[col0 + wc * 64 + n * 16 + lr];
#pragma unroll
          for (int r = 0; r < 4; r++) {
            int row = rbase + r;
            if (row < M) {
              size_t cidx = ilv ? ((size_t)row * 512 + (size_t)(ccol >> 2) * 8 + (ccol & 3) + voff)
                                : ((size_t)row * 256 + ccol);
              C[cidx] = f2b(acc[m][n][r] + bv);
            }
          }
          acc[m][n] = (f32x4){0.f, 0.f, 0.f, 0.f};
        }
      }
    }
    __syncthreads();
  }
}

// out = alpha*(A0@B0^T [+A1@B1^T] + ab) + (1-alpha)*h   (A,B internal bf16)
// merged: blockIdx.y<2 -> author job (N=256, 1 group); y>=2 -> paper job (2 groups)
__global__ __launch_bounds__(256) void out_gemm2(const ushort* __restrict__ Aa,
                                                 const ushort* __restrict__ Ba_,
                                                 const ushort* __restrict__ Ap0,
                                                 const ushort* __restrict__ Bp0,
                                                 const ushort* __restrict__ Ap1,
                                                 const ushort* __restrict__ Bp1,
                                                 const void* __restrict__ ab,
                                                 const void* __restrict__ h_a,
                                                 const void* __restrict__ h_p,
                                                 const void* __restrict__ skipv,
                                                 void* __restrict__ out,
                                                 const int* __restrict__ dtf) {
  const int y = blockIdx.y;
  const int isA = (y < 2);
  const ushort* A0 = isA ? Aa : Ap0;
  const ushort* B0 = isA ? Ba_ : Bp0;
  const ushort* A1 = isA ? nullptr : Ap1;
  const ushort* B1 = isA ? nullptr : Bp1;
  const int ab_off = isA ? 0 : 256;
  const void* h = isA ? h_a : h_p;
  const int skipidx = isA ? 0 : 1;
  const size_t out_off = isA ? 0 : (size_t)NA * DD;
  const int M = isA ? NA : NP;
  const int col0 = (isA ? y : (y - 2)) * 128;
  const int row0 = blockIdx.x * 128;
  if (row0 >= M) return;

  const int isbf = *dtf;
  __shared__ __align__(16) ushort As[2][4096];
  __shared__ __align__(16) ushort Bs[2][4096];
  const int tid = threadIdx.x;
  const int ln = tid & 63, wv = tid >> 6;
  const int quad = ln >> 4, lr = ln & 15;
  const int wr = wv >> 1, wc = wv & 1;

  f32x4 acc[4][4];
#pragma unroll
  for (int m = 0; m < 4; m++)
#pragma unroll
    for (int n = 0; n < 4; n++) acc[m][n] = (f32x4){0.f, 0.f, 0.f, 0.f};

  const int r0 = tid >> 2, seg = tid & 3;
  const int r1 = 64 + r0;
  int ar0 = row0 + r0; if (ar0 >= M) ar0 = M - 1;
  int ar1 = row0 + r1; if (ar1 >= M) ar1 = M - 1;
  const int lbase = (tid & 192) * 8;

  const int nsteps = (A1 != nullptr) ? 16 : 8;
  auto stage = [&](int s, int buf) {
    int g = s >> 3, kb = s & 7;
    const ushort* A = g ? A1 : A0;
    const ushort* B = g ? B1 : B0;
    gload16(A + (size_t)ar0 * 256 + seg * 8 + kb * 32, As[buf] + lbase);
    gload16(A + (size_t)ar1 * 256 + seg * 8 + kb * 32, As[buf] + 2048 + lbase);
    gload16(B + (size_t)(col0 + r0) * 256 + seg * 8 + kb * 32, Bs[buf] + lbase);
    gload16(B + (size_t)(col0 + r1) * 256 + seg * 8 + kb * 32, Bs[buf] + 2048 + lbase);
  };

  stage(0, 0);
  __syncthreads();
  for (int s = 0; s < nsteps; s++) {
    const int cur = s & 1;
    if (s + 1 < nsteps) stage(s + 1, cur ^ 1);
    bf16x8 af[4], bfr[4];
#pragma unroll
    for (int m = 0; m < 4; m++)
      af[m] = *(const bf16x8*)&As[cur][(wr * 64 + m * 16 + lr) * 32 + quad * 8];
#pragma unroll
    for (int n = 0; n < 4; n++)
      bfr[n] = *(const bf16x8*)&Bs[cur][(wc * 64 + n * 16 + lr) * 32 + quad * 8];
#pragma unroll
    for (int m = 0; m < 4; m++)
#pragma unroll
      for (int n = 0; n < 4; n++)
        acc[m][n] = __builtin_amdgcn_mfma_f32_16x16x32_bf16(af[m], bfr[n], acc[m][n], 0, 0, 0);
    __syncthreads();
  }

  float alpha = 1.f / (1.f + __expf(-ldf(skipv, skipidx, isbf)));
  float beta = 1.f - alpha;
#pragma unroll
  for (int m = 0; m < 4; m++) {
    int rbase = row0 + wr * 64 + m * 16 + quad * 4;
#pragma unroll
    for (int n = 0; n < 4; n++) {
      int col = col0 + wc * 64 + n * 16 + lr;
      float bv = ldf(ab, ab_off + col, isbf);
#pragma unroll
      for (int r = 0; r < 4; r++) {
        int row = rbase + r;
        if (row < M) {
          float t = acc[m][n][r] + bv;
          float o = alpha * t + beta * ldf(h, (size_t)row * 256 + col, isbf);
          stf(out, out_off + (size_t)row * 256 + col, o, isbf);
        }
      }
    }
  }
}

// ---------------- CSR build: count -> device-wide scan (3 kernels) -> scatter ----------------
__global__ void count_edges(const int* __restrict__ d0, const int* __restrict__ d1,
                            const int* __restrict__ d2, int* __restrict__ cnt) {
  int i = blockIdx.x * 256 + threadIdx.x;
  if (i >= 3 * NE) return;
  int et = (i >= 2 * NE) ? 2 : ((i >= NE) ? 1 : 0);
  int e = i - et * NE;
  const int* dd = (et == 0) ? d0 : ((et == 1) ? d1 : d2);
  int base = (et == 0) ? 0 : ((et == 1) ? NP : 2 * NP);
  atomicAdd(&cnt[base + dd[e]], 1);
}

__global__ __launch_bounds__(256) void reduce_cnt(const int* __restrict__ cnt,
                                                  int* __restrict__ bsum) {
  __shared__ int red[256];
  int t = threadIdx.x;
  int base = blockIdx.x * 2048 + t * 8;
  int s = 0;
#pragma unroll
  for (int j = 0; j < 8; j++) s += (base + j < NTOT) ? cnt[base + j] : 0;
  red[t] = s;
  __syncthreads();
  for (int o = 128; o > 0; o >>= 1) {
    if (t < o) red[t] += red[t + o];
    __syncthreads();
  }
  if (t == 0) bsum[blockIdx.x] = red[0];
}

__global__ __launch_bounds__(64) void scan_top(const int* __restrict__ bsum,
                                               int* __restrict__ ebase) {
  __shared__ int ts[64];
  int t = threadIdx.x;
  int v = (t < NBLK) ? bsum[t] : 0;
  ts[t] = v;
  __syncthreads();
  for (int o = 1; o < 64; o <<= 1) {
    int x = (t >= o) ? ts[t - o] : 0;
    __syncthreads();
    ts[t] += x;
    __syncthreads();
  }
  if (t < NBLK) ebase[t] = ts[t] - v;  // exclusive
}

__global__ __launch_bounds__(256) void scan_final(const int* __restrict__ cnt,
                                                  const int* __restrict__ ebase,
                                                  int* __restrict__ offs,
                                                  int* __restrict__ cur) {
  __shared__ int ts[256];
  int t = threadIdx.x;
  int base = blockIdx.x * 2048 + t * 8;
  int v[8];
  int s = 0;
#pragma unroll
  for (int j = 0; j < 8; j++) {
    int x = (base + j < NTOT) ? cnt[base + j] : 0;
    v[j] = s;
    s += x;
  }
  ts[t] = s;
  __syncthreads();
  for (int o = 1; o < 256; o <<= 1) {
    int x = (t >= o) ? ts[t - o] : 0;
    __syncthreads();
    ts[t] += x;
    __syncthreads();
  }
  int tb = ebase[blockIdx.x] + ts[t] - s;
#pragma unroll
  for (int j = 0; j < 8; j++) {
    int i = base + j;
    if (i < NTOT) {
      int o2 = tb + v[j];
      offs[i] = o2;
      cur[i] = o2;
    }
  }
  if (blockIdx.x == 0 && t == 0) offs[NTOT] = 3 * NE;
}

__global__ void scatter_edges(const int* __restrict__ s0, const int* __restrict__ d0,
                              const int* __restrict__ s1, const int* __restrict__ d1,
                              const int* __restrict__ s2, const int* __restrict__ d2,
                              int* __restrict__ cur, int* __restrict__ csr) {
  int i = blockIdx.x * 256 + threadIdx.x;
  if (i >= 3 * NE) return;
  int et = (i >= 2 * NE) ? 2 : ((i >= NE) ? 1 : 0);
  int e = i - et * NE;
  const int* ss = (et == 0) ? s0 : ((et == 1) ? s1 : s2);
  const int* dd = (et == 0) ? d0 : ((et == 1) ? d1 : d2);
  int base = (et == 0) ? 0 : ((et == 1) ? NP : 2 * NP);
  int pos = atomicAdd(&cur[base + dd[e]], 1);  // global position in joint CSR
  csr[pos] = ss[e];
}

// ---------------- merged per-dst online-softmax aggregation (one wave per dst) ----------------
// KV layout: row s = 512 ushorts; lane ln's dwordx4 at s*512+ln*8 = {k0..k3, v0..v3}
// Chunked online softmax: 8 edges per iteration; prif folded into q; first chunk
// skips the rescale chain (l,a are zero -> bit-identical).
__global__ __launch_bounds__(256) void edge_agg_all(ushort* __restrict__ Qe0,
                                                    ushort* __restrict__ Qe1,
                                                    ushort* __restrict__ Qe2,
                                                    const ushort* __restrict__ KVa,
                                                    const ushort* __restrict__ KVp,
                                                    const int* __restrict__ offs,
                                                    const int* __restrict__ csr,
                                                    const void* __restrict__ pri,
                                                    const int* __restrict__ dtf) {
  int isbf = *dtf;
  int wv = threadIdx.x >> 6;
  int g = blockIdx.x * 4 + wv;
  if (g >= NTOT) return;
  int ln = threadIdx.x & 63;
  int h = ln >> 3;
  int d, pri_off, n_src;
  ushort* Q;
  const ushort* KV;
  if (g < NP) {
    d = g; Q = Qe0; KV = KVa; pri_off = 0; n_src = NA;
  } else if (g < 2 * NP) {
    d = g - NP; Q = Qe1; KV = KVp; pri_off = 8; n_src = NP;
  } else {
    d = g - 2 * NP; Q = Qe2; KV = KVp; pri_off = 16; n_src = NP;
  }
  float prif = ldf(pri, pri_off + h, isbf) * 0.17677669529663687f;  // 1/sqrt(32)
  ushort4 qu = *(const ushort4*)(Q + (size_t)d * 256 + ln * 4);
  float q0 = b2f(qu.x) * prif, q1 = b2f(qu.y) * prif;
  float q2 = b2f(qu.z) * prif, q3 = b2f(qu.w) * prif;
  float m = -1e30f, l = 0.f;
  float a0 = 0.f, a1 = 0.f, a2 = 0.f, a3 = 0.f;
  int e0 = __builtin_amdgcn_readfirstlane(offs[g]);
  int e1 = __builtin_amdgcn_readfirstlane(offs[g + 1]);
  if (e1 > e0 + 4096) e1 = e0 + 4096;  // firewall

  for (int e = e0; e < e1; e += 8) {
    int nv = e1 - e;
    nv = (nv > 8) ? 8 : nv;  // wave-uniform
    int4 kv[8];
    float sc[8];
#pragma unroll
    for (int i = 0; i < 8; i++) sc[i] = -1e30f;
    // issue all loads first: 8-deep memory pipeline
#pragma unroll
    for (int i = 0; i < 8; i++) {
      if (i < nv) {
        unsigned s = (unsigned)csr[e + i];   // scalar (e uniform)
        if (s >= (unsigned)n_src) s = 0;     // firewall
        kv[i] = *(const int4*)(KV + (size_t)s * 512 + ln * 8);
      }
    }
    // independent dot + reduce per edge
#pragma unroll
    for (int i = 0; i < 8; i++) {
      if (i < nv) {
        float p = q0 * b2f_lo(kv[i].x) + q1 * b2f_hi(kv[i].x) +
                  q2 * b2f_lo(kv[i].y) + q3 * b2f_hi(kv[i].y);
        p += __shfl_xor(p, 1);
        p += __shfl_xor(p, 2);
        p += __shfl_xor(p, 4);
        sc[i] = p;
      }
    }
    // one max-merge + one rescale per chunk (first chunk: l,a zero -> skip)
    float mc = fmaxf(fmaxf(fmaxf(sc[0], sc[1]), fmaxf(sc[2], sc[3])),
                     fmaxf(fmaxf(sc[4], sc[5]), fmaxf(sc[6], sc[7])));
    float mn = fmaxf(m, mc);
    if (e != e0) {
      float scale = __expf(m - mn);
      l *= scale; a0 *= scale; a1 *= scale; a2 *= scale; a3 *= scale;
    }
#pragma unroll
    for (int i = 0; i < 8; i++) {
      if (i < nv) {
        float wgt = __expf(sc[i] - mn);
        l += wgt;
        a0 += wgt * b2f_lo(kv[i].z);
        a1 += wgt * b2f_hi(kv[i].z);
        a2 += wgt * b2f_lo(kv[i].w);
        a3 += wgt * b2f_hi(kv[i].w);
      }
    }
    m = mn;
  }
  float inv = (l > 0.f) ? 1.f / l : 0.f;
  ushort4 o;
  o.x = f2b(a0 * inv);
  o.y = f2b(a1 * inv);
  o.z = f2b(a2 * inv);
  o.w = f2b(a3 * inv);
  *(ushort4*)(Q + (size_t)d * 256 + ln * 4) = o;  // in-place agg
}

// ---------------- launch ----------------
extern "C" void kernel_launch(void* const* d_in, const int* in_sizes, int n_in,
                              void* d_out, int out_size, void* d_ws, size_t ws_size,
                              hipStream_t stream) {
  (void)in_sizes; (void)n_in; (void)out_size; (void)ws_size;
  const void* h_a = d_in[0];
  const void* h_p = d_in[1];
  const void* k_w = d_in[2];
  const void* k_b = d_in[3];
  const void* q_w = d_in[4];
  const void* q_b = d_in[5];
  const void* v_w = d_in[6];
  const void* v_b = d_in[7];
  const void* a_w = d_in[8];
  const void* a_b = d_in[9];
  const void* ratt = d_in[10];
  const void* rmsg = d_in[11];
  const void* rpri = d_in[12];
  const void* skip = d_in[13];
  const int* src_w = (const int*)d_in[14];
  const int* dst_w = (const int*)d_in[15];
  const int* src_c = (const int*)d_in[16];
  const int* dst_c = (const int*)d_in[17];
  const int* src_b = (const int*)d_in[18];
  const int* dst_b = (const int*)d_in[19];

  char* w = (char*)d_ws;
  size_t ofs = 0;
  auto alloc = [&](size_t bytes) {
    char* p = w + ofs;
    ofs = (ofs + bytes + 255) & ~(size_t)255;
    return p;
  };
  int* dtf = (int*)alloc(256);
  ushort* Bp = (ushort*)alloc((size_t)1024 * 256 * 2);  // [kw1; vw1; qeff e0; qeff e1]
  ushort* Ba = (ushort*)alloc((size_t)768 * 256 * 2);   // [kw0; vw0; qeff e2]
  ushort* aeff = (ushort*)alloc((size_t)3 * 256 * 256 * 2);
  float* gb = (float*)alloc((size_t)7 * 256 * 4);
  int* cnt = (int*)alloc((size_t)NTOT * 4);
  int* offs = (int*)alloc((size_t)(NTOT + 1) * 4);
  int* bsum = (int*)alloc(64 * 4);
  int* ebase = (int*)alloc(64 * 4);
  int* cur = (int*)alloc((size_t)NTOT * 4);
  int* csr = (int*)alloc((size_t)3 * NE * 4);
  ushort* Ha = (ushort*)alloc((size_t)NA * DD * 2);    // bf16 h_author
  ushort* Hp = (ushort*)alloc((size_t)NP * DD * 2);    // bf16 h_paper
  ushort* KVa = (ushort*)alloc((size_t)NA * 512 * 2);  // interleaved K/V, author srcs
  ushort* KVp = (ushort*)alloc((size_t)NP * 512 * 2);  // interleaved K/V, paper srcs
  ushort* Qe0 = (ushort*)alloc((size_t)NP * DD * 2);
  ushort* Qe1 = (ushort*)alloc((size_t)NP * DD * 2);
  ushort* Qe2 = (ushort*)alloc((size_t)NA * DD * 2);
  ushort* agg0 = Qe0;  // in-place edge_agg
  ushort* agg1 = Qe1;
  ushort* agg2 = Qe2;

  hipMemsetAsync(cnt, 0, (size_t)NTOT * 4, stream);
  detect_dtype<<<1, 64, 0, stream>>>((const unsigned*)rpri, dtf);

  cvt_h<<<(2240000 + 255) / 256, 256, 0, stream>>>(h_a, h_p, Ha, Hp, dtf);
  build_eff<<<dim3(256, 6), 256, 0, stream>>>(q_w, a_w, ratt, rmsg, Bp, Ba, aeff, dtf);
  make_biases<<<1, 256, 0, stream>>>(k_b, v_b, q_b, ratt, gb, dtf);
  cvt_wt<<<128, 256, 0, stream>>>(k_w, v_w, Bp, Ba, dtf);

  // projections: single launch, 14 col-panel jobs (K/V jobs write interleaved KV)
  GemmC4 cpp, cpa;
  cpp.c[0] = KVp; cpp.ilv[0] = 1;
  cpp.c[1] = KVp; cpp.ilv[1] = 2;
  cpp.c[2] = Qe0; cpp.ilv[2] = 0;
  cpp.c[3] = Qe1; cpp.ilv[3] = 0;
  cpa.c[0] = KVa; cpa.ilv[0] = 1;
  cpa.c[1] = KVa; cpa.ilv[1] = 2;
  cpa.c[2] = Qe2; cpa.ilv[2] = 0;
  cpa.c[3] = Qe2; cpa.ilv[3] = 0;  // unused
  gemm_proj<<<dim3(49, 14), 256, 0, stream>>>(Hp, Ha, Bp, Ba, gb, cpp, cpa);

  // CSR build
  count_edges<<<(3 * NE + 255) / 256, 256, 0, stream>>>(dst_w, dst_c, dst_b, cnt);
  reduce_cnt<<<NBLK, 256, 0, stream>>>(cnt, bsum);
  scan_top<<<1, 64, 0, stream>>>(bsum, ebase);
  scan_final<<<NBLK, 256, 0, stream>>>(cnt, ebase, offs, cur);
  scatter_edges<<<(3 * NE + 255) / 256, 256, 0, stream>>>(src_w, dst_w, src_c, dst_c,
                                                          src_b, dst_b, cur, csr);

  // merged aggregation: one wave per joint dst bucket
  edge_agg_all<<<(NTOT + 3) / 4, 256, 0, stream>>>(Qe0, Qe1, Qe2, KVa, KVp,
                                                   offs, csr, rpri, dtf);

  // merged output GEMM: y<2 author (col panels of 256), y>=2 paper
  out_gemm2<<<dim3((NP + 127) / 128, 4), 256, 0, stream>>>(
      agg2, aeff + 131072, agg0, aeff, agg1, aeff + 65536,
      a_b, h_a, h_p, skip, d_out, dtf);
}

// Round 5
// 669.448 us; speedup vs baseline: 1.1635x; 1.1635x over previous
//
#include <hip/hip_runtime.h>
#include <hip/hip_bf16.h>

#define NA 20000
#define NP 50000
#define NE 300000
#define DD 256
#define HH 8
#define NTOT (2 * NP + NA)           // 120000 joint dst buckets
#define NBLK ((NTOT + 2047) / 2048)  // 59 scan blocks

typedef short bf16x8 __attribute__((ext_vector_type(8)));
typedef float f32x4 __attribute__((ext_vector_type(4)));

__device__ __forceinline__ float b2f(ushort u) {
  unsigned v = ((unsigned)u) << 16;
  float f;
  __builtin_memcpy(&f, &v, 4);
  return f;
}
__device__ __forceinline__ float b2f_lo(int u) {
  unsigned v = ((unsigned)u) << 16;
  float f;
  __builtin_memcpy(&f, &v, 4);
  return f;
}
__device__ __forceinline__ float b2f_hi(int u) {
  unsigned v = ((unsigned)u) & 0xffff0000u;
  float f;
  __builtin_memcpy(&f, &v, 4);
  return f;
}
__device__ __forceinline__ ushort f2b(float f) {
  unsigned u;
  __builtin_memcpy(&u, &f, 4);
  u = u + 0x7fffu + ((u >> 16) & 1u);
  return (ushort)(u >> 16);
}
__device__ __forceinline__ unsigned pk2(float lo, float hi) {
  return (unsigned)f2b(lo) | ((unsigned)f2b(hi) << 16);
}
// dual-dtype scalar load / store (isbf: 1 = bf16, 0 = fp32)
__device__ __forceinline__ float ldf(const void* p, int i, int isbf) {
  return isbf ? b2f(((const ushort*)p)[i]) : ((const float*)p)[i];
}
__device__ __forceinline__ void stf(void* p, size_t i, float v, int isbf) {
  if (isbf) ((ushort*)p)[i] = f2b(v);
  else ((float*)p)[i] = v;
}
// async global->LDS, 16B per lane; LDS dest must be wave-uniform base (+lane*16 implicit)
__device__ __forceinline__ void gload16(const void* g, void* l) {
  __builtin_amdgcn_global_load_lds(
      (const __attribute__((address_space(1))) void*)g,
      (__attribute__((address_space(3))) void*)l, 16, 0, 0);
}

// rel_pri is all-ones: first u32 is 0x3F803F80 if bf16-packed, 0x3F800000 if fp32.
__global__ void detect_dtype(const unsigned* __restrict__ pri, int* __restrict__ dtf) {
  if (threadIdx.x == 0) *dtf = (pri[0] == 0x3F803F80u) ? 1 : 0;
}

// convert h_a / h_p to bf16 tables once (8 elems/thread)
__global__ __launch_bounds__(256) void cvt_h(const void* __restrict__ ha,
                                             const void* __restrict__ hp,
                                             ushort* __restrict__ Ha,
                                             ushort* __restrict__ Hp,
                                             const int* __restrict__ dtf) {
  int isbf = *dtf;
  size_t t = (size_t)blockIdx.x * 256 + threadIdx.x;
  const size_t nA = (size_t)NA * 256 / 8;        // 640000
  const size_t nT = nA + (size_t)NP * 256 / 8;   // 2240000
  if (t >= nT) return;
  const void* src;
  ushort* dst;
  size_t o;
  if (t < nA) { src = ha; dst = Ha; o = t * 8; }
  else        { src = hp; dst = Hp; o = (t - nA) * 8; }
  if (isbf) {
    *(int4*)(dst + o) = *(const int4*)((const ushort*)src + o);
  } else {
    const float* f = (const float*)src + o;
    float4 x = *(const float4*)f;
    float4 y = *(const float4*)(f + 4);
    int4 v;
    v.x = (int)pk2(x.x, x.y); v.y = (int)pk2(x.z, x.w);
    v.z = (int)pk2(y.x, y.y); v.w = (int)pk2(y.z, y.w);
    *(int4*)(dst + o) = v;
  }
}

// fused: y<3 -> Qeff rows into B panels; y>=3 -> Aeff
// Bp rows: [0,256)=kw1 [256,512)=vw1 [512,768)=qeff e0 [768,1024)=qeff e1
// Ba rows: [0,256)=kw0 [256,512)=vw0 [512,768)=qeff e2
__global__ __launch_bounds__(256) void build_eff(const void* __restrict__ q_w,
                                                 const void* __restrict__ a_w,
                                                 const void* __restrict__ ratt,
                                                 const void* __restrict__ rmsg,
                                                 ushort* __restrict__ Bp,
                                                 ushort* __restrict__ Ba,
                                                 ushort* __restrict__ aeff,
                                                 const int* __restrict__ dtf) {
  int isbf = *dtf;
  int y = blockIdx.y;
  int r = blockIdx.x;
  int c = threadIdx.x;
  if (y < 3) {
    int e = y;
    int nt = (e == 2) ? 0 : 1;
    int h = r >> 5, i = r & 31;
    int rb = ((e * HH + h) * 32 + i) * 32;
    int qb = nt * 65536 + (h * 32) * 256 + c;
    float s = 0.f;
#pragma unroll 8
    for (int j = 0; j < 32; j++) s += ldf(ratt, rb + j, isbf) * ldf(q_w, qb + j * 256, isbf);
    ushort* dst = (e == 2) ? (Ba + (size_t)(512 + r) * 256)
                           : (Bp + (size_t)(512 + e * 256 + r) * 256);
    dst[c] = f2b(s);
  } else {
    int e = y - 3;
    int o = r;
    int nt = (e == 2) ? 0 : 1;
    int h = c >> 5, i = c & 31;
    int rb = ((e * HH + h) * 32 + i) * 32;
    int ab = nt * 65536 + o * 256 + h * 32;
    float s = 0.f;
#pragma unroll 8
    for (int j = 0; j < 32; j++) s += ldf(rmsg, rb + j, isbf) * ldf(a_w, ab + j, isbf);
    aeff[(e * 256 + o) * 256 + c] = f2b(s);
  }
}

// convert external k_w/v_w into the bf16 B panels (4 sections x 65536 elems, 8/thread)
__global__ __launch_bounds__(256) void cvt_wt(const void* __restrict__ kw,
                                              const void* __restrict__ vw,
                                              ushort* __restrict__ Bp,
                                              ushort* __restrict__ Ba,
                                              const int* __restrict__ dtf) {
  int isbf = *dtf;
  int t = blockIdx.x * 256 + threadIdx.x;  // 0..32767
  int sec = t >> 13;
  int o = (t & 8191) * 8;
  const void* src = (sec == 0 || sec == 2) ? kw : vw;
  size_t soff = (sec < 2) ? (size_t)(65536 + o) : (size_t)o;
  ushort* dst = (sec == 0) ? (Bp + o)
              : (sec == 1) ? (Bp + 65536 + o)
              : (sec == 2) ? (Ba + o)
                           : (Ba + 65536 + o);
  if (isbf) {
    *(int4*)dst = *(const int4*)((const ushort*)src + soff);
  } else {
    const float* f = (const float*)src + soff;
    float4 x = *(const float4*)f;
    float4 y = *(const float4*)(f + 4);
    int4 v;
    v.x = (int)pk2(x.x, x.y); v.y = (int)pk2(x.z, x.w);
    v.z = (int)pk2(y.x, y.y); v.w = (int)pk2(y.z, y.w);
    *(int4*)dst = v;
  }
}

// gb layout (fp32): [0]=kb1 [1]=vb1 [2]=qeb0 [3]=qeb1 | [4]=kb0 [5]=vb0 [6]=qeb2
__global__ __launch_bounds__(256) void make_biases(const void* __restrict__ k_b,
                                                   const void* __restrict__ v_b,
                                                   const void* __restrict__ q_b,
                                                   const void* __restrict__ ratt,
                                                   float* __restrict__ gb,
                                                   const int* __restrict__ dtf) {
  int isbf = *dtf;
  int c = threadIdx.x;
  gb[0 * 256 + c] = ldf(k_b, 256 + c, isbf);
  gb[1 * 256 + c] = ldf(v_b, 256 + c, isbf);
  gb[4 * 256 + c] = ldf(k_b, c, isbf);
  gb[5 * 256 + c] = ldf(v_b, c, isbf);
  int h = c >> 5, i = c & 31;
  for (int e = 0; e < 3; e++) {
    int ntp = (e == 2) ? 0 : 1;
    int rb = ((e * HH + h) * 32 + i) * 32;
    float s = 0.f;
    for (int j = 0; j < 32; j++)
      s += ldf(ratt, rb + j, isbf) * ldf(q_b, ntp * 256 + h * 32 + j, isbf);
    gb[(e == 2 ? 6 : (2 + e)) * 256 + c] = s;
  }
}

// ---------------- 128x128-tile MFMA GEMM, double-buffered, merged jobs ----------------
// blockIdx.y < 8: NP family (A=Hp, B=Bp, col0=y*128); y >= 8: NA family.
// Blocks with row0 >= M return early (NA tail).
// ilv: 0 = plain [row][256]; 1 = K-half of interleaved KV[row][512]; 2 = V-half.
struct GemmC4 { ushort* c[4]; int ilv[4]; };

__global__ __launch_bounds__(256) void gemm_proj(const ushort* __restrict__ Hp,
                                                 const ushort* __restrict__ Ha,
                                                 const ushort* __restrict__ Bpp,
                                                 const ushort* __restrict__ Bap,
                                                 const float* __restrict__ gb,
                                                 GemmC4 cpp, GemmC4 cpa) {
  const int y = blockIdx.y;
  const int isNP = (y < 8);
  const int M = isNP ? NP : NA;
  const int row0 = blockIdx.x * 128;
  if (row0 >= M) return;
  const ushort* A = isNP ? Hp : Ha;
  const ushort* B = isNP ? Bpp : Bap;
  const float* gbias = isNP ? gb : (gb + 1024);
  const int col0 = (isNP ? y : (y - 8)) * 128;
  const GemmC4 cp = isNP ? cpp : cpa;
  ushort* C = cp.c[col0 >> 8];
  const int ilv = cp.ilv[col0 >> 8];
  const int ccol0 = col0 & 255;

  __shared__ __align__(16) ushort As[2][4096];  // [128][32] bf16, linear
  __shared__ __align__(16) ushort Bs[2][4096];
  const int tid = threadIdx.x;
  const int ln = tid & 63, wv = tid >> 6;
  const int quad = ln >> 4, lr = ln & 15;
  const int wr = wv >> 1, wc = wv & 1;  // 2x2 wave grid over 128x128

  f32x4 acc[4][4];
#pragma unroll
  for (int m = 0; m < 4; m++)
#pragma unroll
    for (int n = 0; n < 4; n++) acc[m][n] = (f32x4){0.f, 0.f, 0.f, 0.f};

  // staging chunk map: thread t stages 16B at LDS ushort t*8 -> row t>>2, seg t&3
  const int r0 = tid >> 2, seg = tid & 3;
  const int r1 = 64 + r0;
  int ar0 = row0 + r0; if (ar0 >= M) ar0 = M - 1;  // clamp; guarded at store
  int ar1 = row0 + r1; if (ar1 >= M) ar1 = M - 1;
  const ushort* gA0 = A + ((size_t)ar0 * 256 + seg * 8);
  const ushort* gA1 = A + ((size_t)ar1 * 256 + seg * 8);
  const ushort* gB0 = B + ((size_t)(col0 + r0) * 256 + seg * 8);
  const ushort* gB1 = B + ((size_t)(col0 + r1) * 256 + seg * 8);
  const int lbase = (tid & 192) * 8;  // wave-uniform LDS ushort offset

  auto stage = [&](int kb, int buf) {
    gload16(gA0 + kb * 32, As[buf] + lbase);
    gload16(gA1 + kb * 32, As[buf] + 2048 + lbase);
    gload16(gB0 + kb * 32, Bs[buf] + lbase);
    gload16(gB1 + kb * 32, Bs[buf] + 2048 + lbase);
  };

  stage(0, 0);
  __syncthreads();
  for (int kb = 0; kb < 8; kb++) {
    const int cur = kb & 1;
    if (kb < 7) stage(kb + 1, cur ^ 1);
    bf16x8 af[4], bfr[4];
#pragma unroll
    for (int m = 0; m < 4; m++)
      af[m] = *(const bf16x8*)&As[cur][(wr * 64 + m * 16 + lr) * 32 + quad * 8];
#pragma unroll
    for (int n = 0; n < 4; n++)
      bfr[n] = *(const bf16x8*)&Bs[cur][(wc * 64 + n * 16 + lr) * 32 + quad * 8];
#pragma unroll
    for (int m = 0; m < 4; m++)
#pragma unroll
      for (int n = 0; n < 4; n++)
        acc[m][n] = __builtin_amdgcn_mfma_f32_16x16x32_bf16(af[m], bfr[n], acc[m][n], 0, 0, 0);
    __syncthreads();  // drains prefetch vmcnt + protects buffer reuse
  }

  const int voff = (ilv == 2) ? 4 : 0;
#pragma unroll
  for (int m = 0; m < 4; m++) {
    int rbase = row0 + wr * 64 + m * 16 + quad * 4;
#pragma unroll
    for (int n = 0; n < 4; n++) {
      int ccol = ccol0 + wc * 64 + n * 16 + lr;
      float bv = gbias[col0 + wc * 64 + n * 16 + lr];
#pragma unroll
      for (int r = 0; r < 4; r++) {
        int row = rbase + r;
        if (row < M) {
          size_t cidx = ilv ? ((size_t)row * 512 + (size_t)(ccol >> 2) * 8 + (ccol & 3) + voff)
                            : ((size_t)row * 256 + ccol);
          C[cidx] = f2b(acc[m][n][r] + bv);
        }
      }
    }
  }
}

// out = alpha*(A0@B0^T [+A1@B1^T] + ab) + (1-alpha)*h   (A,B internal bf16)
// merged: blockIdx.y<2 -> author job (N=256, 1 group); y>=2 -> paper job (2 groups)
__global__ __launch_bounds__(256) void out_gemm2(const ushort* __restrict__ Aa,
                                                 const ushort* __restrict__ Ba_,
                                                 const ushort* __restrict__ Ap0,
                                                 const ushort* __restrict__ Bp0,
                                                 const ushort* __restrict__ Ap1,
                                                 const ushort* __restrict__ Bp1,
                                                 const void* __restrict__ ab,
                                                 const void* __restrict__ h_a,
                                                 const void* __restrict__ h_p,
                                                 const void* __restrict__ skipv,
                                                 void* __restrict__ out,
                                                 const int* __restrict__ dtf) {
  const int y = blockIdx.y;
  const int isA = (y < 2);
  const int M = isA ? NA : NP;
  const int row0 = blockIdx.x * 128;
  if (row0 >= M) return;
  const ushort* A0 = isA ? Aa : Ap0;
  const ushort* B0 = isA ? Ba_ : Bp0;
  const ushort* A1 = isA ? nullptr : Ap1;
  const ushort* B1 = isA ? nullptr : Bp1;
  const int ab_off = isA ? 0 : 256;
  const void* h = isA ? h_a : h_p;
  const int skipidx = isA ? 0 : 1;
  const size_t out_off = isA ? 0 : (size_t)NA * DD;
  const int col0 = (isA ? y : (y - 2)) * 128;

  const int isbf = *dtf;
  __shared__ __align__(16) ushort As[2][4096];
  __shared__ __align__(16) ushort Bs[2][4096];
  const int tid = threadIdx.x;
  const int ln = tid & 63, wv = tid >> 6;
  const int quad = ln >> 4, lr = ln & 15;
  const int wr = wv >> 1, wc = wv & 1;

  f32x4 acc[4][4];
#pragma unroll
  for (int m = 0; m < 4; m++)
#pragma unroll
    for (int n = 0; n < 4; n++) acc[m][n] = (f32x4){0.f, 0.f, 0.f, 0.f};

  const int r0 = tid >> 2, seg = tid & 3;
  const int r1 = 64 + r0;
  int ar0 = row0 + r0; if (ar0 >= M) ar0 = M - 1;
  int ar1 = row0 + r1; if (ar1 >= M) ar1 = M - 1;
  const int lbase = (tid & 192) * 8;

  const int nsteps = (A1 != nullptr) ? 16 : 8;
  auto stage = [&](int s, int buf) {
    int g = s >> 3, kb = s & 7;
    const ushort* A = g ? A1 : A0;
    const ushort* B = g ? B1 : B0;
    gload16(A + (size_t)ar0 * 256 + seg * 8 + kb * 32, As[buf] + lbase);
    gload16(A + (size_t)ar1 * 256 + seg * 8 + kb * 32, As[buf] + 2048 + lbase);
    gload16(B + (size_t)(col0 + r0) * 256 + seg * 8 + kb * 32, Bs[buf] + lbase);
    gload16(B + (size_t)(col0 + r1) * 256 + seg * 8 + kb * 32, Bs[buf] + 2048 + lbase);
  };

  stage(0, 0);
  __syncthreads();
  for (int s = 0; s < nsteps; s++) {
    const int cur = s & 1;
    if (s + 1 < nsteps) stage(s + 1, cur ^ 1);
    bf16x8 af[4], bfr[4];
#pragma unroll
    for (int m = 0; m < 4; m++)
      af[m] = *(const bf16x8*)&As[cur][(wr * 64 + m * 16 + lr) * 32 + quad * 8];
#pragma unroll
    for (int n = 0; n < 4; n++)
      bfr[n] = *(const bf16x8*)&Bs[cur][(wc * 64 + n * 16 + lr) * 32 + quad * 8];
#pragma unroll
    for (int m = 0; m < 4; m++)
#pragma unroll
      for (int n = 0; n < 4; n++)
        acc[m][n] = __builtin_amdgcn_mfma_f32_16x16x32_bf16(af[m], bfr[n], acc[m][n], 0, 0, 0);
    __syncthreads();
  }

  float alpha = 1.f / (1.f + __expf(-ldf(skipv, skipidx, isbf)));
  float beta = 1.f - alpha;
#pragma unroll
  for (int m = 0; m < 4; m++) {
    int rbase = row0 + wr * 64 + m * 16 + quad * 4;
#pragma unroll
    for (int n = 0; n < 4; n++) {
      int col = col0 + wc * 64 + n * 16 + lr;
      float bv = ldf(ab, ab_off + col, isbf);
#pragma unroll
      for (int r = 0; r < 4; r++) {
        int row = rbase + r;
        if (row < M) {
          float t = acc[m][n][r] + bv;
          float o = alpha * t + beta * ldf(h, (size_t)row * 256 + col, isbf);
          stf(out, out_off + (size_t)row * 256 + col, o, isbf);
        }
      }
    }
  }
}

// ---------------- CSR build: count -> device-wide scan (3 kernels) -> scatter ----------------
__global__ void count_edges(const int* __restrict__ d0, const int* __restrict__ d1,
                            const int* __restrict__ d2, int* __restrict__ cnt) {
  int i = blockIdx.x * 256 + threadIdx.x;
  if (i >= 3 * NE) return;
  int et = (i >= 2 * NE) ? 2 : ((i >= NE) ? 1 : 0);
  int e = i - et * NE;
  const int* dd = (et == 0) ? d0 : ((et == 1) ? d1 : d2);
  int base = (et == 0) ? 0 : ((et == 1) ? NP : 2 * NP);
  atomicAdd(&cnt[base + dd[e]], 1);
}

__global__ __launch_bounds__(256) void reduce_cnt(const int* __restrict__ cnt,
                                                  int* __restrict__ bsum) {
  __shared__ int red[256];
  int t = threadIdx.x;
  int base = blockIdx.x * 2048 + t * 8;
  int s = 0;
#pragma unroll
  for (int j = 0; j < 8; j++) s += (base + j < NTOT) ? cnt[base + j] : 0;
  red[t] = s;
  __syncthreads();
  for (int o = 128; o > 0; o >>= 1) {
    if (t < o) red[t] += red[t + o];
    __syncthreads();
  }
  if (t == 0) bsum[blockIdx.x] = red[0];
}

__global__ __launch_bounds__(64) void scan_top(const int* __restrict__ bsum,
                                               int* __restrict__ ebase) {
  __shared__ int ts[64];
  int t = threadIdx.x;
  int v = (t < NBLK) ? bsum[t] : 0;
  ts[t] = v;
  __syncthreads();
  for (int o = 1; o < 64; o <<= 1) {
    int x = (t >= o) ? ts[t - o] : 0;
    __syncthreads();
    ts[t] += x;
    __syncthreads();
  }
  if (t < NBLK) ebase[t] = ts[t] - v;  // exclusive
}

__global__ __launch_bounds__(256) void scan_final(const int* __restrict__ cnt,
                                                  const int* __restrict__ ebase,
                                                  int* __restrict__ offs,
                                                  int* __restrict__ cur) {
  __shared__ int ts[256];
  int t = threadIdx.x;
  int base = blockIdx.x * 2048 + t * 8;
  int v[8];
  int s = 0;
#pragma unroll
  for (int j = 0; j < 8; j++) {
    int x = (base + j < NTOT) ? cnt[base + j] : 0;
    v[j] = s;
    s += x;
  }
  ts[t] = s;
  __syncthreads();
  for (int o = 1; o < 256; o <<= 1) {
    int x = (t >= o) ? ts[t - o] : 0;
    __syncthreads();
    ts[t] += x;
    __syncthreads();
  }
  int tb = ebase[blockIdx.x] + ts[t] - s;
#pragma unroll
  for (int j = 0; j < 8; j++) {
    int i = base + j;
    if (i < NTOT) {
      int o2 = tb + v[j];
      offs[i] = o2;
      cur[i] = o2;
    }
  }
  if (blockIdx.x == 0 && t == 0) offs[NTOT] = 3 * NE;
}

__global__ void scatter_edges(const int* __restrict__ s0, const int* __restrict__ d0,
                              const int* __restrict__ s1, const int* __restrict__ d1,
                              const int* __restrict__ s2, const int* __restrict__ d2,
                              int* __restrict__ cur, int* __restrict__ csr) {
  int i = blockIdx.x * 256 + threadIdx.x;
  if (i >= 3 * NE) return;
  int et = (i >= 2 * NE) ? 2 : ((i >= NE) ? 1 : 0);
  int e = i - et * NE;
  const int* ss = (et == 0) ? s0 : ((et == 1) ? s1 : s2);
  const int* dd = (et == 0) ? d0 : ((et == 1) ? d1 : d2);
  int base = (et == 0) ? 0 : ((et == 1) ? NP : 2 * NP);
  int pos = atomicAdd(&cur[base + dd[e]], 1);  // global position in joint CSR
  csr[pos] = ss[e];
}

// ---------------- merged per-dst online-softmax aggregation (one wave per dst) ----------------
// KV layout: row s = 512 ushorts; lane ln's dwordx4 at s*512+ln*8 = {k0..k3, v0..v3}
// Chunked online softmax: 8 edges per iteration; prif folded into q; first chunk
// skips the rescale chain (l,a are zero -> bit-identical).
__global__ __launch_bounds__(256) void edge_agg_all(ushort* __restrict__ Qe0,
                                                    ushort* __restrict__ Qe1,
                                                    ushort* __restrict__ Qe2,
                                                    const ushort* __restrict__ KVa,
                                                    const ushort* __restrict__ KVp,
                                                    const int* __restrict__ offs,
                                                    const int* __restrict__ csr,
                                                    const void* __restrict__ pri,
                                                    const int* __restrict__ dtf) {
  int isbf = *dtf;
  int wv = threadIdx.x >> 6;
  int g = blockIdx.x * 4 + wv;
  if (g >= NTOT) return;
  int ln = threadIdx.x & 63;
  int h = ln >> 3;
  int d, pri_off, n_src;
  ushort* Q;
  const ushort* KV;
  if (g < NP) {
    d = g; Q = Qe0; KV = KVa; pri_off = 0; n_src = NA;
  } else if (g < 2 * NP) {
    d = g - NP; Q = Qe1; KV = KVp; pri_off = 8; n_src = NP;
  } else {
    d = g - 2 * NP; Q = Qe2; KV = KVp; pri_off = 16; n_src = NP;
  }
  float prif = ldf(pri, pri_off + h, isbf) * 0.17677669529663687f;  // 1/sqrt(32)
  ushort4 qu = *(const ushort4*)(Q + (size_t)d * 256 + ln * 4);
  float q0 = b2f(qu.x) * prif, q1 = b2f(qu.y) * prif;
  float q2 = b2f(qu.z) * prif, q3 = b2f(qu.w) * prif;
  float m = -1e30f, l = 0.f;
  float a0 = 0.f, a1 = 0.f, a2 = 0.f, a3 = 0.f;
  int e0 = __builtin_amdgcn_readfirstlane(offs[g]);
  int e1 = __builtin_amdgcn_readfirstlane(offs[g + 1]);
  if (e1 > e0 + 4096) e1 = e0 + 4096;  // firewall

  for (int e = e0; e < e1; e += 8) {
    int nv = e1 - e;
    nv = (nv > 8) ? 8 : nv;  // wave-uniform
    int4 kv[8];
    float sc[8];
#pragma unroll
    for (int i = 0; i < 8; i++) sc[i] = -1e30f;
    // issue all loads first: 8-deep memory pipeline
#pragma unroll
    for (int i = 0; i < 8; i++) {
      if (i < nv) {
        unsigned s = (unsigned)csr[e + i];   // scalar (e uniform)
        if (s >= (unsigned)n_src) s = 0;     // firewall
        kv[i] = *(const int4*)(KV + (size_t)s * 512 + ln * 8);
      }
    }
    // independent dot + reduce per edge
#pragma unroll
    for (int i = 0; i < 8; i++) {
      if (i < nv) {
        float p = q0 * b2f_lo(kv[i].x) + q1 * b2f_hi(kv[i].x) +
                  q2 * b2f_lo(kv[i].y) + q3 * b2f_hi(kv[i].y);
        p += __shfl_xor(p, 1);
        p += __shfl_xor(p, 2);
        p += __shfl_xor(p, 4);
        sc[i] = p;
      }
    }
    // one max-merge + one rescale per chunk (first chunk: l,a zero -> skip)
    float mc = fmaxf(fmaxf(fmaxf(sc[0], sc[1]), fmaxf(sc[2], sc[3])),
                     fmaxf(fmaxf(sc[4], sc[5]), fmaxf(sc[6], sc[7])));
    float mn = fmaxf(m, mc);
    if (e != e0) {
      float scale = __expf(m - mn);
      l *= scale; a0 *= scale; a1 *= scale; a2 *= scale; a3 *= scale;
    }
#pragma unroll
    for (int i = 0; i < 8; i++) {
      if (i < nv) {
        float wgt = __expf(sc[i] - mn);
        l += wgt;
        a0 += wgt * b2f_lo(kv[i].z);
        a1 += wgt * b2f_hi(kv[i].z);
        a2 += wgt * b2f_lo(kv[i].w);
        a3 += wgt * b2f_hi(kv[i].w);
      }
    }
    m = mn;
  }
  float inv = (l > 0.f) ? 1.f / l : 0.f;
  ushort4 o;
  o.x = f2b(a0 * inv);
  o.y = f2b(a1 * inv);
  o.z = f2b(a2 * inv);
  o.w = f2b(a3 * inv);
  *(ushort4*)(Q + (size_t)d * 256 + ln * 4) = o;  // in-place agg
}

// ---------------- launch ----------------
extern "C" void kernel_launch(void* const* d_in, const int* in_sizes, int n_in,
                              void* d_out, int out_size, void* d_ws, size_t ws_size,
                              hipStream_t stream) {
  (void)in_sizes; (void)n_in; (void)out_size; (void)ws_size;
  const void* h_a = d_in[0];
  const void* h_p = d_in[1];
  const void* k_w = d_in[2];
  const void* k_b = d_in[3];
  const void* q_w = d_in[4];
  const void* q_b = d_in[5];
  const void* v_w = d_in[6];
  const void* v_b = d_in[7];
  const void* a_w = d_in[8];
  const void* a_b = d_in[9];
  const void* ratt = d_in[10];
  const void* rmsg = d_in[11];
  const void* rpri = d_in[12];
  const void* skip = d_in[13];
  const int* src_w = (const int*)d_in[14];
  const int* dst_w = (const int*)d_in[15];
  const int* src_c = (const int*)d_in[16];
  const int* dst_c = (const int*)d_in[17];
  const int* src_b = (const int*)d_in[18];
  const int* dst_b = (const int*)d_in[19];

  char* w = (char*)d_ws;
  size_t ofs = 0;
  auto alloc = [&](size_t bytes) {
    char* p = w + ofs;
    ofs = (ofs + bytes + 255) & ~(size_t)255;
    return p;
  };
  int* dtf = (int*)alloc(256);
  ushort* Bp = (ushort*)alloc((size_t)1024 * 256 * 2);  // [kw1; vw1; qeff e0; qeff e1]
  ushort* Ba = (ushort*)alloc((size_t)768 * 256 * 2);   // [kw0; vw0; qeff e2]
  ushort* aeff = (ushort*)alloc((size_t)3 * 256 * 256 * 2);
  float* gb = (float*)alloc((size_t)7 * 256 * 4);
  int* cnt = (int*)alloc((size_t)NTOT * 4);
  int* offs = (int*)alloc((size_t)(NTOT + 1) * 4);
  int* bsum = (int*)alloc(64 * 4);
  int* ebase = (int*)alloc(64 * 4);
  int* cur = (int*)alloc((size_t)NTOT * 4);
  int* csr = (int*)alloc((size_t)3 * NE * 4);
  ushort* Ha = (ushort*)alloc((size_t)NA * DD * 2);    // bf16 h_author
  ushort* Hp = (ushort*)alloc((size_t)NP * DD * 2);    // bf16 h_paper
  ushort* KVa = (ushort*)alloc((size_t)NA * 512 * 2);  // interleaved K/V, author srcs
  ushort* KVp = (ushort*)alloc((size_t)NP * 512 * 2);  // interleaved K/V, paper srcs
  ushort* Qe0 = (ushort*)alloc((size_t)NP * DD * 2);
  ushort* Qe1 = (ushort*)alloc((size_t)NP * DD * 2);
  ushort* Qe2 = (ushort*)alloc((size_t)NA * DD * 2);
  ushort* agg0 = Qe0;  // in-place edge_agg
  ushort* agg1 = Qe1;
  ushort* agg2 = Qe2;

  hipMemsetAsync(cnt, 0, (size_t)NTOT * 4, stream);
  detect_dtype<<<1, 64, 0, stream>>>((const unsigned*)rpri, dtf);

  cvt_h<<<(2240000 + 255) / 256, 256, 0, stream>>>(h_a, h_p, Ha, Hp, dtf);
  build_eff<<<dim3(256, 6), 256, 0, stream>>>(q_w, a_w, ratt, rmsg, Bp, Ba, aeff, dtf);
  make_biases<<<1, 256, 0, stream>>>(k_b, v_b, q_b, ratt, gb, dtf);
  cvt_wt<<<128, 256, 0, stream>>>(k_w, v_w, Bp, Ba, dtf);

  // projections: single merged launch, 14 col-panel jobs (K/V jobs -> interleaved KV)
  GemmC4 cpp, cpa;
  cpp.c[0] = KVp; cpp.ilv[0] = 1;
  cpp.c[1] = KVp; cpp.ilv[1] = 2;
  cpp.c[2] = Qe0; cpp.ilv[2] = 0;
  cpp.c[3] = Qe1; cpp.ilv[3] = 0;
  cpa.c[0] = KVa; cpa.ilv[0] = 1;
  cpa.c[1] = KVa; cpa.ilv[1] = 2;
  cpa.c[2] = Qe2; cpa.ilv[2] = 0;
  cpa.c[3] = Qe2; cpa.ilv[3] = 0;  // unused
  gemm_proj<<<dim3((NP + 127) / 128, 14), 256, 0, stream>>>(Hp, Ha, Bp, Ba, gb, cpp, cpa);

  // CSR build
  count_edges<<<(3 * NE + 255) / 256, 256, 0, stream>>>(dst_w, dst_c, dst_b, cnt);
  reduce_cnt<<<NBLK, 256, 0, stream>>>(cnt, bsum);
  scan_top<<<1, 64, 0, stream>>>(bsum, ebase);
  scan_final<<<NBLK, 256, 0, stream>>>(cnt, ebase, offs, cur);
  scatter_edges<<<(3 * NE + 255) / 256, 256, 0, stream>>>(src_w, dst_w, src_c, dst_c,
                                                          src_b, dst_b, cur, csr);

  // merged aggregation: one wave per joint dst bucket
  edge_agg_all<<<(NTOT + 3) / 4, 256, 0, stream>>>(Qe0, Qe1, Qe2, KVa, KVp,
                                                   offs, csr, rpri, dtf);

  // merged output GEMM: y<2 author (col panels of 256), y>=2 paper
  out_gemm2<<<dim3((NP + 127) / 128, 4), 256, 0, stream>>>(
      agg2, aeff + 131072, agg0, aeff, agg1, aeff + 65536,
      a_b, h_a, h_p, skip, d_out, dtf);
}

// Round 6
// 659.914 us; speedup vs baseline: 1.1804x; 1.0144x over previous
//
#include <hip/hip_runtime.h>
#include <hip/hip_bf16.h>

#define NA 20000
#define NP 50000
#define NE 300000
#define DD 256
#define HH 8
#define NTOT (2 * NP + NA)           // 120000 joint dst buckets
#define NBLK ((NTOT + 2047) / 2048)  // 59 scan blocks
#define NRT 391                      // ceil(NP/128) row tiles

typedef short bf16x8 __attribute__((ext_vector_type(8)));
typedef float f32x4 __attribute__((ext_vector_type(4)));

__device__ __forceinline__ float b2f(ushort u) {
  unsigned v = ((unsigned)u) << 16;
  float f;
  __builtin_memcpy(&f, &v, 4);
  return f;
}
__device__ __forceinline__ float b2f_lo(int u) {
  unsigned v = ((unsigned)u) << 16;
  float f;
  __builtin_memcpy(&f, &v, 4);
  return f;
}
__device__ __forceinline__ float b2f_hi(int u) {
  unsigned v = ((unsigned)u) & 0xffff0000u;
  float f;
  __builtin_memcpy(&f, &v, 4);
  return f;
}
__device__ __forceinline__ ushort f2b(float f) {
  unsigned u;
  __builtin_memcpy(&u, &f, 4);
  u = u + 0x7fffu + ((u >> 16) & 1u);
  return (ushort)(u >> 16);
}
__device__ __forceinline__ unsigned pk2(float lo, float hi) {
  return (unsigned)f2b(lo) | ((unsigned)f2b(hi) << 16);
}
// dual-dtype scalar load / store (isbf: 1 = bf16, 0 = fp32)
__device__ __forceinline__ float ldf(const void* p, int i, int isbf) {
  return isbf ? b2f(((const ushort*)p)[i]) : ((const float*)p)[i];
}
__device__ __forceinline__ void stf(void* p, size_t i, float v, int isbf) {
  if (isbf) ((ushort*)p)[i] = f2b(v);
  else ((float*)p)[i] = v;
}
// rel_pri is all-ones: first u32 is 0x3F803F80 if bf16-packed, 0x3F800000 if fp32.
__device__ __forceinline__ int get_isbf(const void* rpri) {
  return ((const unsigned*)rpri)[0] == 0x3F803F80u;
}
// async global->LDS, 16B per lane; LDS dest must be wave-uniform base (+lane*16 implicit)
__device__ __forceinline__ void gload16(const void* g, void* l) {
  __builtin_amdgcn_global_load_lds(
      (const __attribute__((address_space(1))) void*)g,
      (__attribute__((address_space(3))) void*)l, 16, 0, 0);
}

// convert h_a / h_p to bf16 tables once (8 elems/thread)
__global__ __launch_bounds__(256) void cvt_h(const void* __restrict__ ha,
                                             const void* __restrict__ hp,
                                             ushort* __restrict__ Ha,
                                             ushort* __restrict__ Hp,
                                             const void* __restrict__ rpri) {
  int isbf = get_isbf(rpri);
  size_t t = (size_t)blockIdx.x * 256 + threadIdx.x;
  const size_t nA = (size_t)NA * 256 / 8;        // 640000
  const size_t nT = nA + (size_t)NP * 256 / 8;   // 2240000
  if (t >= nT) return;
  const void* src;
  ushort* dst;
  size_t o;
  if (t < nA) { src = ha; dst = Ha; o = t * 8; }
  else        { src = hp; dst = Hp; o = (t - nA) * 8; }
  if (isbf) {
    *(int4*)(dst + o) = *(const int4*)((const ushort*)src + o);
  } else {
    const float* f = (const float*)src + o;
    float4 x = *(const float4*)f;
    float4 y = *(const float4*)(f + 4);
    int4 v;
    v.x = (int)pk2(x.x, x.y); v.y = (int)pk2(x.z, x.w);
    v.z = (int)pk2(y.x, y.y); v.w = (int)pk2(y.z, y.w);
    *(int4*)(dst + o) = v;
  }
}

// fused prep: y<3 -> Qeff rows into B panels; y in 3..5 -> Aeff;
//             y==6: x<128 -> cvt k_w/v_w into panels, x==128 -> biases
// Bp rows: [0,256)=kw1 [256,512)=vw1 [512,768)=qeff e0 [768,1024)=qeff e1
// Ba rows: [0,256)=kw0 [256,512)=vw0 [512,768)=qeff e2
// gb (fp32): [0]=kb1 [1]=vb1 [2]=qeb0 [3]=qeb1 | [4]=kb0 [5]=vb0 [6]=qeb2
__global__ __launch_bounds__(256) void prep(const void* __restrict__ q_w,
                                            const void* __restrict__ a_w,
                                            const void* __restrict__ k_w,
                                            const void* __restrict__ v_w,
                                            const void* __restrict__ k_b,
                                            const void* __restrict__ v_b,
                                            const void* __restrict__ q_b,
                                            const void* __restrict__ ratt,
                                            const void* __restrict__ rmsg,
                                            ushort* __restrict__ Bp,
                                            ushort* __restrict__ Ba,
                                            ushort* __restrict__ aeff,
                                            float* __restrict__ gb,
                                            const void* __restrict__ rpri) {
  int isbf = get_isbf(rpri);
  int y = blockIdx.y;
  int r = blockIdx.x;
  int c = threadIdx.x;
  if (y < 3) {
    int e = y;
    int nt = (e == 2) ? 0 : 1;
    int h = r >> 5, i = r & 31;
    int rb = ((e * HH + h) * 32 + i) * 32;
    int qb = nt * 65536 + (h * 32) * 256 + c;
    float s = 0.f;
#pragma unroll 8
    for (int j = 0; j < 32; j++) s += ldf(ratt, rb + j, isbf) * ldf(q_w, qb + j * 256, isbf);
    ushort* dst = (e == 2) ? (Ba + (size_t)(512 + r) * 256)
                           : (Bp + (size_t)(512 + e * 256 + r) * 256);
    dst[c] = f2b(s);
  } else if (y < 6) {
    int e = y - 3;
    int o = r;
    int nt = (e == 2) ? 0 : 1;
    int h = c >> 5, i = c & 31;
    int rb = ((e * HH + h) * 32 + i) * 32;
    int ab = nt * 65536 + o * 256 + h * 32;
    float s = 0.f;
#pragma unroll 8
    for (int j = 0; j < 32; j++) s += ldf(rmsg, rb + j, isbf) * ldf(a_w, ab + j, isbf);
    aeff[(e * 256 + o) * 256 + c] = f2b(s);
  } else if (r < 128) {
    // k_w/v_w -> bf16 panels (4 sections x 65536 elems, 8/thread)
    int t = r * 256 + c;  // 0..32767
    int sec = t >> 13;
    int o = (t & 8191) * 8;
    const void* src = (sec == 0 || sec == 2) ? k_w : v_w;
    size_t soff = (sec < 2) ? (size_t)(65536 + o) : (size_t)o;
    ushort* dst = (sec == 0) ? (Bp + o)
                : (sec == 1) ? (Bp + 65536 + o)
                : (sec == 2) ? (Ba + o)
                             : (Ba + 65536 + o);
    if (isbf) {
      *(int4*)dst = *(const int4*)((const ushort*)src + soff);
    } else {
      const float* f = (const float*)src + soff;
      float4 x = *(const float4*)f;
      float4 yy = *(const float4*)(f + 4);
      int4 v;
      v.x = (int)pk2(x.x, x.y); v.y = (int)pk2(x.z, x.w);
      v.z = (int)pk2(yy.x, yy.y); v.w = (int)pk2(yy.z, yy.w);
      *(int4*)dst = v;
    }
  } else if (r == 128) {
    gb[0 * 256 + c] = ldf(k_b, 256 + c, isbf);
    gb[1 * 256 + c] = ldf(v_b, 256 + c, isbf);
    gb[4 * 256 + c] = ldf(k_b, c, isbf);
    gb[5 * 256 + c] = ldf(v_b, c, isbf);
    int h = c >> 5, i = c & 31;
    for (int e = 0; e < 3; e++) {
      int ntp = (e == 2) ? 0 : 1;
      int rb = ((e * HH + h) * 32 + i) * 32;
      float s = 0.f;
      for (int j = 0; j < 32; j++)
        s += ldf(ratt, rb + j, isbf) * ldf(q_b, ntp * 256 + h * 32 + j, isbf);
      gb[(e == 2 ? 6 : (2 + e)) * 256 + c] = s;
    }
  }
}

// ---------------- 128x128-tile MFMA GEMM, double-buffered, merged jobs ----------------
// 1-D grid with XCD-aware decode: all 14 col-panel jobs of one A row-tile land on
// the same XCD back-to-back -> A row-tile stays in that XCD's L2 (fetched once).
// job y < 8: NP family (A=Hp, B=Bp, col0=y*128); y >= 8: NA family.
// ilv: 0 = plain [row][256]; 1 = K-half of interleaved KV[row][512]; 2 = V-half.
struct GemmC4 { ushort* c[4]; int ilv[4]; };

__global__ __launch_bounds__(256) void gemm_proj(const ushort* __restrict__ Hp,
                                                 const ushort* __restrict__ Ha,
                                                 const ushort* __restrict__ Bpp,
                                                 const ushort* __restrict__ Bap,
                                                 const float* __restrict__ gb,
                                                 GemmC4 cpp, GemmC4 cpa) {
  const int bid = blockIdx.x;
  const int xcd = bid & 7, seq = bid >> 3;
  const int rt = (seq / 14) * 8 + xcd;   // row tile: same rt x all jobs -> same XCD
  const int y = seq % 14;                // col-panel job
  if (rt >= NRT) return;
  const int isNP = (y < 8);
  const int M = isNP ? NP : NA;
  const int row0 = rt * 128;
  if (row0 >= M) return;
  const ushort* A = isNP ? Hp : Ha;
  const ushort* B = isNP ? Bpp : Bap;
  const float* gbias = isNP ? gb : (gb + 1024);
  const int col0 = (isNP ? y : (y - 8)) * 128;
  const GemmC4 cp = isNP ? cpp : cpa;
  ushort* C = cp.c[col0 >> 8];
  const int ilv = cp.ilv[col0 >> 8];
  const int ccol0 = col0 & 255;

  __shared__ __align__(16) ushort As[2][4096];  // [128][32] bf16, linear
  __shared__ __align__(16) ushort Bs[2][4096];
  const int tid = threadIdx.x;
  const int ln = tid & 63, wv = tid >> 6;
  const int quad = ln >> 4, lr = ln & 15;
  const int wr = wv >> 1, wc = wv & 1;  // 2x2 wave grid over 128x128

  f32x4 acc[4][4];
#pragma unroll
  for (int m = 0; m < 4; m++)
#pragma unroll
    for (int n = 0; n < 4; n++) acc[m][n] = (f32x4){0.f, 0.f, 0.f, 0.f};

  // staging chunk map: thread t stages 16B at LDS ushort t*8 -> row t>>2, seg t&3
  const int r0 = tid >> 2, seg = tid & 3;
  const int r1 = 64 + r0;
  int ar0 = row0 + r0; if (ar0 >= M) ar0 = M - 1;  // clamp; guarded at store
  int ar1 = row0 + r1; if (ar1 >= M) ar1 = M - 1;
  const ushort* gA0 = A + ((size_t)ar0 * 256 + seg * 8);
  const ushort* gA1 = A + ((size_t)ar1 * 256 + seg * 8);
  const ushort* gB0 = B + ((size_t)(col0 + r0) * 256 + seg * 8);
  const ushort* gB1 = B + ((size_t)(col0 + r1) * 256 + seg * 8);
  const int lbase = (tid & 192) * 8;  // wave-uniform LDS ushort offset

  auto stage = [&](int kb, int buf) {
    gload16(gA0 + kb * 32, As[buf] + lbase);
    gload16(gA1 + kb * 32, As[buf] + 2048 + lbase);
    gload16(gB0 + kb * 32, Bs[buf] + lbase);
    gload16(gB1 + kb * 32, Bs[buf] + 2048 + lbase);
  };

  stage(0, 0);
  __syncthreads();
  for (int kb = 0; kb < 8; kb++) {
    const int cur = kb & 1;
    if (kb < 7) stage(kb + 1, cur ^ 1);
    bf16x8 af[4], bfr[4];
#pragma unroll
    for (int m = 0; m < 4; m++)
      af[m] = *(const bf16x8*)&As[cur][(wr * 64 + m * 16 + lr) * 32 + quad * 8];
#pragma unroll
    for (int n = 0; n < 4; n++)
      bfr[n] = *(const bf16x8*)&Bs[cur][(wc * 64 + n * 16 + lr) * 32 + quad * 8];
#pragma unroll
    for (int m = 0; m < 4; m++)
#pragma unroll
      for (int n = 0; n < 4; n++)
        acc[m][n] = __builtin_amdgcn_mfma_f32_16x16x32_bf16(af[m], bfr[n], acc[m][n], 0, 0, 0);
    __syncthreads();  // drains prefetch vmcnt + protects buffer reuse
  }

  const int voff = (ilv == 2) ? 4 : 0;
#pragma unroll
  for (int m = 0; m < 4; m++) {
    int rbase = row0 + wr * 64 + m * 16 + quad * 4;
#pragma unroll
    for (int n = 0; n < 4; n++) {
      int ccol = ccol0 + wc * 64 + n * 16 + lr;
      float bv = gbias[col0 + wc * 64 + n * 16 + lr];
#pragma unroll
      for (int r = 0; r < 4; r++) {
        int row = rbase + r;
        if (row < M) {
          size_t cidx = ilv ? ((size_t)row * 512 + (size_t)(ccol >> 2) * 8 + (ccol & 3) + voff)
                            : ((size_t)row * 256 + ccol);
          C[cidx] = f2b(acc[m][n][r] + bv);
        }
      }
    }
  }
}

// out = alpha*(A0@B0^T [+A1@B1^T] + ab) + (1-alpha)*h   (A,B internal bf16)
// 1-D grid, XCD-aware decode (4 jobs per row-tile on one XCD).
// job y<2 -> author (N=256, 1 group); y>=2 -> paper (2 groups)
__global__ __launch_bounds__(256) void out_gemm2(const ushort* __restrict__ Aa,
                                                 const ushort* __restrict__ Ba_,
                                                 const ushort* __restrict__ Ap0,
                                                 const ushort* __restrict__ Bp0,
                                                 const ushort* __restrict__ Ap1,
                                                 const ushort* __restrict__ Bp1,
                                                 const void* __restrict__ ab,
                                                 const void* __restrict__ h_a,
                                                 const void* __restrict__ h_p,
                                                 const void* __restrict__ skipv,
                                                 void* __restrict__ out,
                                                 const void* __restrict__ rpri) {
  const int bid = blockIdx.x;
  const int xcd = bid & 7, seq = bid >> 3;
  const int rt = (seq / 4) * 8 + xcd;
  const int y = seq & 3;
  if (rt >= NRT) return;
  const int isA = (y < 2);
  const int M = isA ? NA : NP;
  const int row0 = rt * 128;
  if (row0 >= M) return;
  const ushort* A0 = isA ? Aa : Ap0;
  const ushort* B0 = isA ? Ba_ : Bp0;
  const ushort* A1 = isA ? nullptr : Ap1;
  const ushort* B1 = isA ? nullptr : Bp1;
  const int ab_off = isA ? 0 : 256;
  const void* h = isA ? h_a : h_p;
  const int skipidx = isA ? 0 : 1;
  const size_t out_off = isA ? 0 : (size_t)NA * DD;
  const int col0 = (isA ? y : (y - 2)) * 128;

  const int isbf = get_isbf(rpri);
  __shared__ __align__(16) ushort As[2][4096];
  __shared__ __align__(16) ushort Bs[2][4096];
  const int tid = threadIdx.x;
  const int ln = tid & 63, wv = tid >> 6;
  const int quad = ln >> 4, lr = ln & 15;
  const int wr = wv >> 1, wc = wv & 1;

  f32x4 acc[4][4];
#pragma unroll
  for (int m = 0; m < 4; m++)
#pragma unroll
    for (int n = 0; n < 4; n++) acc[m][n] = (f32x4){0.f, 0.f, 0.f, 0.f};

  const int r0 = tid >> 2, seg = tid & 3;
  const int r1 = 64 + r0;
  int ar0 = row0 + r0; if (ar0 >= M) ar0 = M - 1;
  int ar1 = row0 + r1; if (ar1 >= M) ar1 = M - 1;
  const int lbase = (tid & 192) * 8;

  const int nsteps = (A1 != nullptr) ? 16 : 8;
  auto stage = [&](int s, int buf) {
    int g = s >> 3, kb = s & 7;
    const ushort* A = g ? A1 : A0;
    const ushort* B = g ? B1 : B0;
    gload16(A + (size_t)ar0 * 256 + seg * 8 + kb * 32, As[buf] + lbase);
    gload16(A + (size_t)ar1 * 256 + seg * 8 + kb * 32, As[buf] + 2048 + lbase);
    gload16(B + (size_t)(col0 + r0) * 256 + seg * 8 + kb * 32, Bs[buf] + lbase);
    gload16(B + (size_t)(col0 + r1) * 256 + seg * 8 + kb * 32, Bs[buf] + 2048 + lbase);
  };

  stage(0, 0);
  __syncthreads();
  for (int s = 0; s < nsteps; s++) {
    const int cur = s & 1;
    if (s + 1 < nsteps) stage(s + 1, cur ^ 1);
    bf16x8 af[4], bfr[4];
#pragma unroll
    for (int m = 0; m < 4; m++)
      af[m] = *(const bf16x8*)&As[cur][(wr * 64 + m * 16 + lr) * 32 + quad * 8];
#pragma unroll
    for (int n = 0; n < 4; n++)
      bfr[n] = *(const bf16x8*)&Bs[cur][(wc * 64 + n * 16 + lr) * 32 + quad * 8];
#pragma unroll
    for (int m = 0; m < 4; m++)
#pragma unroll
      for (int n = 0; n < 4; n++)
        acc[m][n] = __builtin_amdgcn_mfma_f32_16x16x32_bf16(af[m], bfr[n], acc[m][n], 0, 0, 0);
    __syncthreads();
  }

  float alpha = 1.f / (1.f + __expf(-ldf(skipv, skipidx, isbf)));
  float beta = 1.f - alpha;
#pragma unroll
  for (int m = 0; m < 4; m++) {
    int rbase = row0 + wr * 64 + m * 16 + quad * 4;
#pragma unroll
    for (int n = 0; n < 4; n++) {
      int col = col0 + wc * 64 + n * 16 + lr;
      float bv = ldf(ab, ab_off + col, isbf);
#pragma unroll
      for (int r = 0; r < 4; r++) {
        int row = rbase + r;
        if (row < M) {
          float t = acc[m][n][r] + bv;
          float o = alpha * t + beta * ldf(h, (size_t)row * 256 + col, isbf);
          stf(out, out_off + (size_t)row * 256 + col, o, isbf);
        }
      }
    }
  }
}

// ---------------- CSR build: count -> device-wide scan (3 kernels) -> scatter ----------------
__global__ void count_edges(const int* __restrict__ d0, const int* __restrict__ d1,
                            const int* __restrict__ d2, int* __restrict__ cnt) {
  int i = blockIdx.x * 256 + threadIdx.x;
  if (i >= 3 * NE) return;
  int et = (i >= 2 * NE) ? 2 : ((i >= NE) ? 1 : 0);
  int e = i - et * NE;
  const int* dd = (et == 0) ? d0 : ((et == 1) ? d1 : d2);
  int base = (et == 0) ? 0 : ((et == 1) ? NP : 2 * NP);
  atomicAdd(&cnt[base + dd[e]], 1);
}

__global__ __launch_bounds__(256) void reduce_cnt(const int* __restrict__ cnt,
                                                  int* __restrict__ bsum) {
  __shared__ int red[256];
  int t = threadIdx.x;
  int base = blockIdx.x * 2048 + t * 8;
  int s = 0;
#pragma unroll
  for (int j = 0; j < 8; j++) s += (base + j < NTOT) ? cnt[base + j] : 0;
  red[t] = s;
  __syncthreads();
  for (int o = 128; o > 0; o >>= 1) {
    if (t < o) red[t] += red[t + o];
    __syncthreads();
  }
  if (t == 0) bsum[blockIdx.x] = red[0];
}

__global__ __launch_bounds__(64) void scan_top(const int* __restrict__ bsum,
                                               int* __restrict__ ebase) {
  __shared__ int ts[64];
  int t = threadIdx.x;
  int v = (t < NBLK) ? bsum[t] : 0;
  ts[t] = v;
  __syncthreads();
  for (int o = 1; o < 64; o <<= 1) {
    int x = (t >= o) ? ts[t - o] : 0;
    __syncthreads();
    ts[t] += x;
    __syncthreads();
  }
  if (t < NBLK) ebase[t] = ts[t] - v;  // exclusive
}

__global__ __launch_bounds__(256) void scan_final(const int* __restrict__ cnt,
                                                  const int* __restrict__ ebase,
                                                  int* __restrict__ offs,
                                                  int* __restrict__ cur) {
  __shared__ int ts[256];
  int t = threadIdx.x;
  int base = blockIdx.x * 2048 + t * 8;
  int v[8];
  int s = 0;
#pragma unroll
  for (int j = 0; j < 8; j++) {
    int x = (base + j < NTOT) ? cnt[base + j] : 0;
    v[j] = s;
    s += x;
  }
  ts[t] = s;
  __syncthreads();
  for (int o = 1; o < 256; o <<= 1) {
    int x = (t >= o) ? ts[t - o] : 0;
    __syncthreads();
    ts[t] += x;
    __syncthreads();
  }
  int tb = ebase[blockIdx.x] + ts[t] - s;
#pragma unroll
  for (int j = 0; j < 8; j++) {
    int i = base + j;
    if (i < NTOT) {
      int o2 = tb + v[j];
      offs[i] = o2;
      cur[i] = o2;
    }
  }
  if (blockIdx.x == 0 && t == 0) offs[NTOT] = 3 * NE;
}

__global__ void scatter_edges(const int* __restrict__ s0, const int* __restrict__ d0,
                              const int* __restrict__ s1, const int* __restrict__ d1,
                              const int* __restrict__ s2, const int* __restrict__ d2,
                              int* __restrict__ cur, int* __restrict__ csr) {
  int i = blockIdx.x * 256 + threadIdx.x;
  if (i >= 3 * NE) return;
  int et = (i >= 2 * NE) ? 2 : ((i >= NE) ? 1 : 0);
  int e = i - et * NE;
  const int* ss = (et == 0) ? s0 : ((et == 1) ? s1 : s2);
  const int* dd = (et == 0) ? d0 : ((et == 1) ? d1 : d2);
  int base = (et == 0) ? 0 : ((et == 1) ? NP : 2 * NP);
  int pos = atomicAdd(&cur[base + dd[e]], 1);  // global position in joint CSR
  csr[pos] = ss[e];
}

// ---------------- merged per-dst online-softmax aggregation (one wave per dst) ----------------
// KV layout: row s = 512 ushorts; lane ln's dwordx4 at s*512+ln*8 = {k0..k3, v0..v3}
// Chunked online softmax: 8 edges per iteration; prif folded into q; first chunk
// skips the rescale chain (l,a are zero -> bit-identical).
__global__ __launch_bounds__(256) void edge_agg_all(ushort* __restrict__ Qe0,
                                                    ushort* __restrict__ Qe1,
                                                    ushort* __restrict__ Qe2,
                                                    const ushort* __restrict__ KVa,
                                                    const ushort* __restrict__ KVp,
                                                    const int* __restrict__ offs,
                                                    const int* __restrict__ csr,
                                                    const void* __restrict__ pri) {
  int isbf = get_isbf(pri);
  int wv = threadIdx.x >> 6;
  int g = blockIdx.x * 4 + wv;
  if (g >= NTOT) return;
  int ln = threadIdx.x & 63;
  int h = ln >> 3;
  int d, pri_off, n_src;
  ushort* Q;
  const ushort* KV;
  if (g < NP) {
    d = g; Q = Qe0; KV = KVa; pri_off = 0; n_src = NA;
  } else if (g < 2 * NP) {
    d = g - NP; Q = Qe1; KV = KVp; pri_off = 8; n_src = NP;
  } else {
    d = g - 2 * NP; Q = Qe2; KV = KVp; pri_off = 16; n_src = NP;
  }
  float prif = ldf(pri, pri_off + h, isbf) * 0.17677669529663687f;  // 1/sqrt(32)
  ushort4 qu = *(const ushort4*)(Q + (size_t)d * 256 + ln * 4);
  float q0 = b2f(qu.x) * prif, q1 = b2f(qu.y) * prif;
  float q2 = b2f(qu.z) * prif, q3 = b2f(qu.w) * prif;
  float m = -1e30f, l = 0.f;
  float a0 = 0.f, a1 = 0.f, a2 = 0.f, a3 = 0.f;
  int e0 = __builtin_amdgcn_readfirstlane(offs[g]);
  int e1 = __builtin_amdgcn_readfirstlane(offs[g + 1]);
  if (e1 > e0 + 4096) e1 = e0 + 4096;  // firewall

  for (int e = e0; e < e1; e += 8) {
    int nv = e1 - e;
    nv = (nv > 8) ? 8 : nv;  // wave-uniform
    int4 kv[8];
    float sc[8];
#pragma unroll
    for (int i = 0; i < 8; i++) sc[i] = -1e30f;
    // issue all loads first: 8-deep memory pipeline
#pragma unroll
    for (int i = 0; i < 8; i++) {
      if (i < nv) {
        unsigned s = (unsigned)csr[e + i];   // scalar (e uniform)
        if (s >= (unsigned)n_src) s = 0;     // firewall
        kv[i] = *(const int4*)(KV + (size_t)s * 512 + ln * 8);
      }
    }
    // independent dot + reduce per edge
#pragma unroll
    for (int i = 0; i < 8; i++) {
      if (i < nv) {
        float p = q0 * b2f_lo(kv[i].x) + q1 * b2f_hi(kv[i].x) +
                  q2 * b2f_lo(kv[i].y) + q3 * b2f_hi(kv[i].y);
        p += __shfl_xor(p, 1);
        p += __shfl_xor(p, 2);
        p += __shfl_xor(p, 4);
        sc[i] = p;
      }
    }
    // one max-merge + one rescale per chunk (first chunk: l,a zero -> skip)
    float mc = fmaxf(fmaxf(fmaxf(sc[0], sc[1]), fmaxf(sc[2], sc[3])),
                     fmaxf(fmaxf(sc[4], sc[5]), fmaxf(sc[6], sc[7])));
    float mn = fmaxf(m, mc);
    if (e != e0) {
      float scale = __expf(m - mn);
      l *= scale; a0 *= scale; a1 *= scale; a2 *= scale; a3 *= scale;
    }
#pragma unroll
    for (int i = 0; i < 8; i++) {
      if (i < nv) {
        float wgt = __expf(sc[i] - mn);
        l += wgt;
        a0 += wgt * b2f_lo(kv[i].z);
        a1 += wgt * b2f_hi(kv[i].z);
        a2 += wgt * b2f_lo(kv[i].w);
        a3 += wgt * b2f_hi(kv[i].w);
      }
    }
    m = mn;
  }
  float inv = (l > 0.f) ? 1.f / l : 0.f;
  ushort4 o;
  o.x = f2b(a0 * inv);
  o.y = f2b(a1 * inv);
  o.z = f2b(a2 * inv);
  o.w = f2b(a3 * inv);
  *(ushort4*)(Q + (size_t)d * 256 + ln * 4) = o;  // in-place agg
}

// ---------------- launch ----------------
extern "C" void kernel_launch(void* const* d_in, const int* in_sizes, int n_in,
                              void* d_out, int out_size, void* d_ws, size_t ws_size,
                              hipStream_t stream) {
  (void)in_sizes; (void)n_in; (void)out_size; (void)ws_size;
  const void* h_a = d_in[0];
  const void* h_p = d_in[1];
  const void* k_w = d_in[2];
  const void* k_b = d_in[3];
  const void* q_w = d_in[4];
  const void* q_b = d_in[5];
  const void* v_w = d_in[6];
  const void* v_b = d_in[7];
  const void* a_w = d_in[8];
  const void* a_b = d_in[9];
  const void* ratt = d_in[10];
  const void* rmsg = d_in[11];
  const void* rpri = d_in[12];
  const void* skip = d_in[13];
  const int* src_w = (const int*)d_in[14];
  const int* dst_w = (const int*)d_in[15];
  const int* src_c = (const int*)d_in[16];
  const int* dst_c = (const int*)d_in[17];
  const int* src_b = (const int*)d_in[18];
  const int* dst_b = (const int*)d_in[19];

  char* w = (char*)d_ws;
  size_t ofs = 0;
  auto alloc = [&](size_t bytes) {
    char* p = w + ofs;
    ofs = (ofs + bytes + 255) & ~(size_t)255;
    return p;
  };
  ushort* Bp = (ushort*)alloc((size_t)1024 * 256 * 2);  // [kw1; vw1; qeff e0; qeff e1]
  ushort* Ba = (ushort*)alloc((size_t)768 * 256 * 2);   // [kw0; vw0; qeff e2]
  ushort* aeff = (ushort*)alloc((size_t)3 * 256 * 256 * 2);
  float* gb = (float*)alloc((size_t)7 * 256 * 4);
  int* cnt = (int*)alloc((size_t)NTOT * 4);
  int* offs = (int*)alloc((size_t)(NTOT + 1) * 4);
  int* bsum = (int*)alloc(64 * 4);
  int* ebase = (int*)alloc(64 * 4);
  int* cur = (int*)alloc((size_t)NTOT * 4);
  int* csr = (int*)alloc((size_t)3 * NE * 4);
  ushort* Ha = (ushort*)alloc((size_t)NA * DD * 2);    // bf16 h_author
  ushort* Hp = (ushort*)alloc((size_t)NP * DD * 2);    // bf16 h_paper
  ushort* KVa = (ushort*)alloc((size_t)NA * 512 * 2);  // interleaved K/V, author srcs
  ushort* KVp = (ushort*)alloc((size_t)NP * 512 * 2);  // interleaved K/V, paper srcs
  ushort* Qe0 = (ushort*)alloc((size_t)NP * DD * 2);
  ushort* Qe1 = (ushort*)alloc((size_t)NP * DD * 2);
  ushort* Qe2 = (ushort*)alloc((size_t)NA * DD * 2);
  ushort* agg0 = Qe0;  // in-place edge_agg
  ushort* agg1 = Qe1;
  ushort* agg2 = Qe2;

  hipMemsetAsync(cnt, 0, (size_t)NTOT * 4, stream);

  cvt_h<<<(2240000 + 255) / 256, 256, 0, stream>>>(h_a, h_p, Ha, Hp, rpri);
  prep<<<dim3(256, 7), 256, 0, stream>>>(q_w, a_w, k_w, v_w, k_b, v_b, q_b,
                                         ratt, rmsg, Bp, Ba, aeff, gb, rpri);

  // projections: single merged launch, XCD-aware (rt,job) decode
  GemmC4 cpp, cpa;
  cpp.c[0] = KVp; cpp.ilv[0] = 1;
  cpp.c[1] = KVp; cpp.ilv[1] = 2;
  cpp.c[2] = Qe0; cpp.ilv[2] = 0;
  cpp.c[3] = Qe1; cpp.ilv[3] = 0;
  cpa.c[0] = KVa; cpa.ilv[0] = 1;
  cpa.c[1] = KVa; cpa.ilv[1] = 2;
  cpa.c[2] = Qe2; cpa.ilv[2] = 0;
  cpa.c[3] = Qe2; cpa.ilv[3] = 0;  // unused
  gemm_proj<<<8 * 50 * 14, 256, 0, stream>>>(Hp, Ha, Bp, Ba, gb, cpp, cpa);

  // CSR build
  count_edges<<<(3 * NE + 255) / 256, 256, 0, stream>>>(dst_w, dst_c, dst_b, cnt);
  reduce_cnt<<<NBLK, 256, 0, stream>>>(cnt, bsum);
  scan_top<<<1, 64, 0, stream>>>(bsum, ebase);
  scan_final<<<NBLK, 256, 0, stream>>>(cnt, ebase, offs, cur);
  scatter_edges<<<(3 * NE + 255) / 256, 256, 0, stream>>>(src_w, dst_w, src_c, dst_c,
                                                          src_b, dst_b, cur, csr);

  // merged aggregation: one wave per joint dst bucket
  edge_agg_all<<<(NTOT + 3) / 4, 256, 0, stream>>>(Qe0, Qe1, Qe2, KVa, KVp,
                                                   offs, csr, rpri);

  // merged output GEMM, XCD-aware decode: y<2 author, y>=2 paper
  out_gemm2<<<8 * 50 * 4, 256, 0, stream>>>(
      agg2, aeff + 131072, agg0, aeff, agg1, aeff + 65536,
      a_b, h_a, h_p, skip, d_out, rpri);
}

// Round 8
// 583.024 us; speedup vs baseline: 1.3360x; 1.1319x over previous
//
#include <hip/hip_runtime.h>
#include <hip/hip_bf16.h>

#define NA 20000
#define NP 50000
#define NE 300000
#define DD 256
#define HH 8
#define NTOT (2 * NP + NA)           // 120000 joint dst buckets
#define NBLK ((NTOT + 2047) / 2048)  // 59 scan blocks
#define NRT 391                      // ceil(NP/128) row tiles

typedef short bf16x8 __attribute__((ext_vector_type(8)));
typedef float f32x4 __attribute__((ext_vector_type(4)));

__device__ __forceinline__ float b2f(ushort u) {
  unsigned v = ((unsigned)u) << 16;
  float f;
  __builtin_memcpy(&f, &v, 4);
  return f;
}
__device__ __forceinline__ float b2f_lo(int u) {
  unsigned v = ((unsigned)u) << 16;
  float f;
  __builtin_memcpy(&f, &v, 4);
  return f;
}
__device__ __forceinline__ float b2f_hi(int u) {
  unsigned v = ((unsigned)u) & 0xffff0000u;
  float f;
  __builtin_memcpy(&f, &v, 4);
  return f;
}
__device__ __forceinline__ ushort f2b(float f) {
  unsigned u;
  __builtin_memcpy(&u, &f, 4);
  u = u + 0x7fffu + ((u >> 16) & 1u);
  return (ushort)(u >> 16);
}
__device__ __forceinline__ unsigned pk2(float lo, float hi) {
  return (unsigned)f2b(lo) | ((unsigned)f2b(hi) << 16);
}
// dual-dtype scalar load / store (isbf: 1 = bf16, 0 = fp32)
__device__ __forceinline__ float ldf(const void* p, int i, int isbf) {
  return isbf ? b2f(((const ushort*)p)[i]) : ((const float*)p)[i];
}
// rel_pri is all-ones: first u32 is 0x3F803F80 if bf16-packed, 0x3F800000 if fp32.
__device__ __forceinline__ int get_isbf(const void* rpri) {
  return ((const unsigned*)rpri)[0] == 0x3F803F80u;
}
// async global->LDS, 16B per lane; LDS dest must be wave-uniform base (+lane*16 implicit)
__device__ __forceinline__ void gload16(const void* g, void* l) {
  __builtin_amdgcn_global_load_lds(
      (const __attribute__((address_space(1))) void*)g,
      (__attribute__((address_space(3))) void*)l, 16, 0, 0);
}

// convert h_a / h_p to bf16 tables once (8 elems/thread)
__global__ __launch_bounds__(256) void cvt_h(const void* __restrict__ ha,
                                             const void* __restrict__ hp,
                                             ushort* __restrict__ Ha,
                                             ushort* __restrict__ Hp,
                                             const void* __restrict__ rpri) {
  int isbf = get_isbf(rpri);
  size_t t = (size_t)blockIdx.x * 256 + threadIdx.x;
  const size_t nA = (size_t)NA * 256 / 8;        // 640000
  const size_t nT = nA + (size_t)NP * 256 / 8;   // 2240000
  if (t >= nT) return;
  const void* src;
  ushort* dst;
  size_t o;
  if (t < nA) { src = ha; dst = Ha; o = t * 8; }
  else        { src = hp; dst = Hp; o = (t - nA) * 8; }
  if (isbf) {
    *(int4*)(dst + o) = *(const int4*)((const ushort*)src + o);
  } else {
    const float* f = (const float*)src + o;
    float4 x = *(const float4*)f;
    float4 y = *(const float4*)(f + 4);
    int4 v;
    v.x = (int)pk2(x.x, x.y); v.y = (int)pk2(x.z, x.w);
    v.z = (int)pk2(y.x, y.y); v.w = (int)pk2(y.z, y.w);
    *(int4*)(dst + o) = v;
  }
}

// fused prep: y<3 -> Qeff rows into B panels; y in 3..5 -> Aeff;
//             y==6: x<128 -> cvt k_w/v_w into panels, x==128 -> biases
// Bp rows: [0,256)=kw1 [256,512)=vw1 [512,768)=qeff e0 [768,1024)=qeff e1
// Ba rows: [0,256)=kw0 [256,512)=vw0 [512,768)=qeff e2
// gb (fp32): [0]=kb1 [1]=vb1 [2]=qeb0 [3]=qeb1 | [4]=kb0 [5]=vb0 [6]=qeb2
__global__ __launch_bounds__(256) void prep(const void* __restrict__ q_w,
                                            const void* __restrict__ a_w,
                                            const void* __restrict__ k_w,
                                            const void* __restrict__ v_w,
                                            const void* __restrict__ k_b,
                                            const void* __restrict__ v_b,
                                            const void* __restrict__ q_b,
                                            const void* __restrict__ ratt,
                                            const void* __restrict__ rmsg,
                                            ushort* __restrict__ Bp,
                                            ushort* __restrict__ Ba,
                                            ushort* __restrict__ aeff,
                                            float* __restrict__ gb,
                                            const void* __restrict__ rpri) {
  int isbf = get_isbf(rpri);
  int y = blockIdx.y;
  int r = blockIdx.x;
  int c = threadIdx.x;
  if (y < 3) {
    int e = y;
    int nt = (e == 2) ? 0 : 1;
    int h = r >> 5, i = r & 31;
    int rb = ((e * HH + h) * 32 + i) * 32;
    int qb = nt * 65536 + (h * 32) * 256 + c;
    float s = 0.f;
#pragma unroll 8
    for (int j = 0; j < 32; j++) s += ldf(ratt, rb + j, isbf) * ldf(q_w, qb + j * 256, isbf);
    ushort* dst = (e == 2) ? (Ba + (size_t)(512 + r) * 256)
                           : (Bp + (size_t)(512 + e * 256 + r) * 256);
    dst[c] = f2b(s);
  } else if (y < 6) {
    int e = y - 3;
    int o = r;
    int nt = (e == 2) ? 0 : 1;
    int h = c >> 5, i = c & 31;
    int rb = ((e * HH + h) * 32 + i) * 32;
    int ab = nt * 65536 + o * 256 + h * 32;
    float s = 0.f;
#pragma unroll 8
    for (int j = 0; j < 32; j++) s += ldf(rmsg, rb + j, isbf) * ldf(a_w, ab + j, isbf);
    aeff[(e * 256 + o) * 256 + c] = f2b(s);
  } else if (r < 128) {
    // k_w/v_w -> bf16 panels (4 sections x 65536 elems, 8/thread)
    int t = r * 256 + c;  // 0..32767
    int sec = t >> 13;
    int o = (t & 8191) * 8;
    const void* src = (sec == 0 || sec == 2) ? k_w : v_w;
    size_t soff = (sec < 2) ? (size_t)(65536 + o) : (size_t)o;
    ushort* dst = (sec == 0) ? (Bp + o)
                : (sec == 1) ? (Bp + 65536 + o)
                : (sec == 2) ? (Ba + o)
                             : (Ba + 65536 + o);
    if (isbf) {
      *(int4*)dst = *(const int4*)((const ushort*)src + soff);
    } else {
      const float* f = (const float*)src + soff;
      float4 x = *(const float4*)f;
      float4 yy = *(const float4*)(f + 4);
      int4 v;
      v.x = (int)pk2(x.x, x.y); v.y = (int)pk2(x.z, x.w);
      v.z = (int)pk2(yy.x, yy.y); v.w = (int)pk2(yy.z, yy.w);
      *(int4*)dst = v;
    }
  } else if (r == 128) {
    gb[0 * 256 + c] = ldf(k_b, 256 + c, isbf);
    gb[1 * 256 + c] = ldf(v_b, 256 + c, isbf);
    gb[4 * 256 + c] = ldf(k_b, c, isbf);
    gb[5 * 256 + c] = ldf(v_b, c, isbf);
    int h = c >> 5, i = c & 31;
    for (int e = 0; e < 3; e++) {
      int ntp = (e == 2) ? 0 : 1;
      int rb = ((e * HH + h) * 32 + i) * 32;
      float s = 0.f;
      for (int j = 0; j < 32; j++)
        s += ldf(ratt, rb + j, isbf) * ldf(q_b, ntp * 256 + h * 32 + j, isbf);
      gb[(e == 2 ? 6 : (2 + e)) * 256 + c] = s;
    }
  }
}

// ---------------- 128x128-tile MFMA GEMM, double-buffered, merged jobs ----------------
// Operand-swapped MFMA (acc = mfma(B,A)): lane holds one row x 4 consecutive cols
// -> vectorized ushort4 C stores. 1-D grid, XCD-aware decode (14 jobs/row-tile on
// one XCD -> A row-tile L2 reuse). job y<8: NP family; y>=8: NA family.
// ilv: 0 = plain [row][256]; 1 = K-half of interleaved KV[row][512]; 2 = V-half.
struct GemmC4 { ushort* c[4]; int ilv[4]; };

__global__ __launch_bounds__(256) void gemm_proj(const ushort* __restrict__ Hp,
                                                 const ushort* __restrict__ Ha,
                                                 const ushort* __restrict__ Bpp,
                                                 const ushort* __restrict__ Bap,
                                                 const float* __restrict__ gb,
                                                 GemmC4 cpp, GemmC4 cpa) {
  const int bid = blockIdx.x;
  const int xcd = bid & 7, seq = bid >> 3;
  const int rt = (seq / 14) * 8 + xcd;   // row tile: same rt x all jobs -> same XCD
  const int y = seq % 14;                // col-panel job
  if (rt >= NRT) return;
  const int isNP = (y < 8);
  const int M = isNP ? NP : NA;
  const int row0 = rt * 128;
  if (row0 >= M) return;
  const ushort* A = isNP ? Hp : Ha;
  const ushort* B = isNP ? Bpp : Bap;
  const float* gbias = isNP ? gb : (gb + 1024);
  const int col0 = (isNP ? y : (y - 8)) * 128;
  const GemmC4 cp = isNP ? cpp : cpa;
  ushort* C = cp.c[col0 >> 8];
  const int ilv = cp.ilv[col0 >> 8];
  const int ccol0 = col0 & 255;

  __shared__ __align__(16) ushort As[2][4096];  // [128][32] bf16, linear
  __shared__ __align__(16) ushort Bs[2][4096];
  const int tid = threadIdx.x;
  const int ln = tid & 63, wv = tid >> 6;
  const int quad = ln >> 4, lr = ln & 15;
  const int wr = wv >> 1, wc = wv & 1;  // 2x2 wave grid over 128x128

  f32x4 acc[4][4];
#pragma unroll
  for (int m = 0; m < 4; m++)
#pragma unroll
    for (int n = 0; n < 4; n++) acc[m][n] = (f32x4){0.f, 0.f, 0.f, 0.f};

  // staging chunk map: thread t stages 16B at LDS ushort t*8 -> row t>>2, seg t&3
  const int r0 = tid >> 2, seg = tid & 3;
  const int r1 = 64 + r0;
  int ar0 = row0 + r0; if (ar0 >= M) ar0 = M - 1;  // clamp; guarded at store
  int ar1 = row0 + r1; if (ar1 >= M) ar1 = M - 1;
  const ushort* gA0 = A + ((size_t)ar0 * 256 + seg * 8);
  const ushort* gA1 = A + ((size_t)ar1 * 256 + seg * 8);
  const ushort* gB0 = B + ((size_t)(col0 + r0) * 256 + seg * 8);
  const ushort* gB1 = B + ((size_t)(col0 + r1) * 256 + seg * 8);
  const int lbase = (tid & 192) * 8;  // wave-uniform LDS ushort offset

  auto stage = [&](int kb, int buf) {
    gload16(gA0 + kb * 32, As[buf] + lbase);
    gload16(gA1 + kb * 32, As[buf] + 2048 + lbase);
    gload16(gB0 + kb * 32, Bs[buf] + lbase);
    gload16(gB1 + kb * 32, Bs[buf] + 2048 + lbase);
  };

  stage(0, 0);
  __syncthreads();
  for (int kb = 0; kb < 8; kb++) {
    const int cur = kb & 1;
    if (kb < 7) stage(kb + 1, cur ^ 1);
    bf16x8 af[4], bfr[4];
#pragma unroll
    for (int m = 0; m < 4; m++)
      af[m] = *(const bf16x8*)&As[cur][(wr * 64 + m * 16 + lr) * 32 + quad * 8];
#pragma unroll
    for (int n = 0; n < 4; n++)
      bfr[n] = *(const bf16x8*)&Bs[cur][(wc * 64 + n * 16 + lr) * 32 + quad * 8];
    // swapped operands: D^T fragments -> lane = (row: m*16+lr, cols: n*16+quad*4+r)
#pragma unroll
    for (int m = 0; m < 4; m++)
#pragma unroll
      for (int n = 0; n < 4; n++)
        acc[m][n] = __builtin_amdgcn_mfma_f32_16x16x32_bf16(bfr[n], af[m], acc[m][n], 0, 0, 0);
    __syncthreads();  // drains prefetch vmcnt + protects buffer reuse
  }

  const int voff = (ilv == 2) ? 4 : 0;
#pragma unroll
  for (int m = 0; m < 4; m++) {
    int row = row0 + wr * 64 + m * 16 + lr;
    if (row >= M) continue;
#pragma unroll
    for (int n = 0; n < 4; n++) {
      int ccol = ccol0 + wc * 64 + n * 16 + quad * 4;  // 4-aligned
      int gcol = col0 + wc * 64 + n * 16 + quad * 4;
      float4 bv = *(const float4*)(gbias + gcol);
      ushort4 o;
      o.x = f2b(acc[m][n][0] + bv.x);
      o.y = f2b(acc[m][n][1] + bv.y);
      o.z = f2b(acc[m][n][2] + bv.z);
      o.w = f2b(acc[m][n][3] + bv.w);
      size_t cidx = ilv ? ((size_t)row * 512 + (size_t)(ccol >> 2) * 8 + voff)
                        : ((size_t)row * 256 + ccol);
      *(ushort4*)(C + cidx) = o;  // 8B-aligned in all cases
    }
  }
}

// out = alpha*(A0@B0^T [+A1@B1^T] + ab) + (1-alpha)*h   (A,B internal bf16)
// 2-D grid (XCD decode reverted: R6 showed it hurt here). Operand-swapped MFMA
// -> float4/ushort4 epilogue (vectorized h load + out store).
// job y<2 -> author (N=256, 1 group); y>=2 -> paper (2 groups)
__global__ __launch_bounds__(256) void out_gemm2(const ushort* __restrict__ Aa,
                                                 const ushort* __restrict__ Ba_,
                                                 const ushort* __restrict__ Ap0,
                                                 const ushort* __restrict__ Bp0,
                                                 const ushort* __restrict__ Ap1,
                                                 const ushort* __restrict__ Bp1,
                                                 const void* __restrict__ ab,
                                                 const void* __restrict__ h_a,
                                                 const void* __restrict__ h_p,
                                                 const void* __restrict__ skipv,
                                                 void* __restrict__ out,
                                                 const void* __restrict__ rpri) {
  const int y = blockIdx.y;
  const int isA = (y < 2);
  const int M = isA ? NA : NP;
  const int row0 = blockIdx.x * 128;
  if (row0 >= M) return;
  const ushort* A0 = isA ? Aa : Ap0;
  const ushort* B0 = isA ? Ba_ : Bp0;
  const ushort* A1 = isA ? nullptr : Ap1;
  const ushort* B1 = isA ? nullptr : Bp1;
  const int ab_off = isA ? 0 : 256;
  const void* h = isA ? h_a : h_p;
  const int skipidx = isA ? 0 : 1;
  const size_t out_off = isA ? 0 : (size_t)NA * DD;
  const int col0 = (isA ? y : (y - 2)) * 128;

  const int isbf = get_isbf(rpri);
  __shared__ __align__(16) ushort As[2][4096];
  __shared__ __align__(16) ushort Bs[2][4096];
  const int tid = threadIdx.x;
  const int ln = tid & 63, wv = tid >> 6;
  const int quad = ln >> 4, lr = ln & 15;
  const int wr = wv >> 1, wc = wv & 1;

  f32x4 acc[4][4];
#pragma unroll
  for (int m = 0; m < 4; m++)
#pragma unroll
    for (int n = 0; n < 4; n++) acc[m][n] = (f32x4){0.f, 0.f, 0.f, 0.f};

  const int r0 = tid >> 2, seg = tid & 3;
  const int r1 = 64 + r0;
  int ar0 = row0 + r0; if (ar0 >= M) ar0 = M - 1;
  int ar1 = row0 + r1; if (ar1 >= M) ar1 = M - 1;
  const int lbase = (tid & 192) * 8;

  const int nsteps = (A1 != nullptr) ? 16 : 8;
  auto stage = [&](int s, int buf) {
    int g = s >> 3, kb = s & 7;
    const ushort* A = g ? A1 : A0;
    const ushort* B = g ? B1 : B0;
    gload16(A + (size_t)ar0 * 256 + seg * 8 + kb * 32, As[buf] + lbase);
    gload16(A + (size_t)ar1 * 256 + seg * 8 + kb * 32, As[buf] + 2048 + lbase);
    gload16(B + (size_t)(col0 + r0) * 256 + seg * 8 + kb * 32, Bs[buf] + lbase);
    gload16(B + (size_t)(col0 + r1) * 256 + seg * 8 + kb * 32, Bs[buf] + 2048 + lbase);
  };

  stage(0, 0);
  __syncthreads();
  for (int s = 0; s < nsteps; s++) {
    const int cur = s & 1;
    if (s + 1 < nsteps) stage(s + 1, cur ^ 1);
    bf16x8 af[4], bfr[4];
#pragma unroll
    for (int m = 0; m < 4; m++)
      af[m] = *(const bf16x8*)&As[cur][(wr * 64 + m * 16 + lr) * 32 + quad * 8];
#pragma unroll
    for (int n = 0; n < 4; n++)
      bfr[n] = *(const bf16x8*)&Bs[cur][(wc * 64 + n * 16 + lr) * 32 + quad * 8];
#pragma unroll
    for (int m = 0; m < 4; m++)
#pragma unroll
      for (int n = 0; n < 4; n++)
        acc[m][n] = __builtin_amdgcn_mfma_f32_16x16x32_bf16(bfr[n], af[m], acc[m][n], 0, 0, 0);
    __syncthreads();
  }

  float alpha = 1.f / (1.f + __expf(-ldf(skipv, skipidx, isbf)));
  float beta = 1.f - alpha;
#pragma unroll
  for (int m = 0; m < 4; m++) {
    int row = row0 + wr * 64 + m * 16 + lr;
    if (row >= M) continue;
#pragma unroll
    for (int n = 0; n < 4; n++) {
      int col = col0 + wc * 64 + n * 16 + quad * 4;  // 4-aligned
      size_t base = (size_t)row * 256 + col;
      float t0 = acc[m][n][0] + ldf(ab, ab_off + col + 0, isbf);
      float t1 = acc[m][n][1] + ldf(ab, ab_off + col + 1, isbf);
      float t2 = acc[m][n][2] + ldf(ab, ab_off + col + 2, isbf);
      float t3 = acc[m][n][3] + ldf(ab, ab_off + col + 3, isbf);
      if (isbf) {
        ushort4 hu = *(const ushort4*)((const ushort*)h + base);
        ushort4 o;
        o.x = f2b(alpha * t0 + beta * b2f(hu.x));
        o.y = f2b(alpha * t1 + beta * b2f(hu.y));
        o.z = f2b(alpha * t2 + beta * b2f(hu.z));
        o.w = f2b(alpha * t3 + beta * b2f(hu.w));
        *(ushort4*)((ushort*)out + out_off + base) = o;
      } else {
        float4 hf = *(const float4*)((const float*)h + base);
        float4 o;
        o.x = alpha * t0 + beta * hf.x;
        o.y = alpha * t1 + beta * hf.y;
        o.z = alpha * t2 + beta * hf.z;
        o.w = alpha * t3 + beta * hf.w;
        *(float4*)((float*)out + out_off + base) = o;
      }
    }
  }
}

// ---------------- CSR build: count -> device-wide scan (3 kernels) -> scatter ----------------
__global__ void count_edges(const int* __restrict__ d0, const int* __restrict__ d1,
                            const int* __restrict__ d2, int* __restrict__ cnt) {
  int i = blockIdx.x * 256 + threadIdx.x;
  if (i >= 3 * NE) return;
  int et = (i >= 2 * NE) ? 2 : ((i >= NE) ? 1 : 0);
  int e = i - et * NE;
  const int* dd = (et == 0) ? d0 : ((et == 1) ? d1 : d2);
  int base = (et == 0) ? 0 : ((et == 1) ? NP : 2 * NP);
  atomicAdd(&cnt[base + dd[e]], 1);
}

__global__ __launch_bounds__(256) void reduce_cnt(const int* __restrict__ cnt,
                                                  int* __restrict__ bsum) {
  __shared__ int red[256];
  int t = threadIdx.x;
  int base = blockIdx.x * 2048 + t * 8;
  int s = 0;
#pragma unroll
  for (int j = 0; j < 8; j++) s += (base + j < NTOT) ? cnt[base + j] : 0;
  red[t] = s;
  __syncthreads();
  for (int o = 128; o > 0; o >>= 1) {
    if (t < o) red[t] += red[t + o];
    __syncthreads();
  }
  if (t == 0) bsum[blockIdx.x] = red[0];
}

__global__ __launch_bounds__(64) void scan_top(const int* __restrict__ bsum,
                                               int* __restrict__ ebase) {
  __shared__ int ts[64];
  int t = threadIdx.x;
  int v = (t < NBLK) ? bsum[t] : 0;
  ts[t] = v;
  __syncthreads();
  for (int o = 1; o < 64; o <<= 1) {
    int x = (t >= o) ? ts[t - o] : 0;
    __syncthreads();
    ts[t] += x;
    __syncthreads();
  }
  if (t < NBLK) ebase[t] = ts[t] - v;  // exclusive
}

__global__ __launch_bounds__(256) void scan_final(const int* __restrict__ cnt,
                                                  const int* __restrict__ ebase,
                                                  int* __restrict__ offs,
                                                  int* __restrict__ cur) {
  __shared__ int ts[256];
  int t = threadIdx.x;
  int base = blockIdx.x * 2048 + t * 8;
  int v[8];
  int s = 0;
#pragma unroll
  for (int j = 0; j < 8; j++) {
    int x = (base + j < NTOT) ? cnt[base + j] : 0;
    v[j] = s;
    s += x;
  }
  ts[t] = s;
  __syncthreads();
  for (int o = 1; o < 256; o <<= 1) {
    int x = (t >= o) ? ts[t - o] : 0;
    __syncthreads();
    ts[t] += x;
    __syncthreads();
  }
  int tb = ebase[blockIdx.x] + ts[t] - s;
#pragma unroll
  for (int j = 0; j < 8; j++) {
    int i = base + j;
    if (i < NTOT) {
      int o2 = tb + v[j];
      offs[i] = o2;
      cur[i] = o2;
    }
  }
  if (blockIdx.x == 0 && t == 0) offs[NTOT] = 3 * NE;
}

__global__ void scatter_edges(const int* __restrict__ s0, const int* __restrict__ d0,
                              const int* __restrict__ s1, const int* __restrict__ d1,
                              const int* __restrict__ s2, const int* __restrict__ d2,
                              int* __restrict__ cur, int* __restrict__ csr) {
  int i = blockIdx.x * 256 + threadIdx.x;
  if (i >= 3 * NE) return;
  int et = (i >= 2 * NE) ? 2 : ((i >= NE) ? 1 : 0);
  int e = i - et * NE;
  const int* ss = (et == 0) ? s0 : ((et == 1) ? s1 : s2);
  const int* dd = (et == 0) ? d0 : ((et == 1) ? d1 : d2);
  int base = (et == 0) ? 0 : ((et == 1) ? NP : 2 * NP);
  int pos = atomicAdd(&cur[base + dd[e]], 1);  // global position in joint CSR
  csr[pos] = ss[e];
}

// ---------------- merged per-dst online-softmax aggregation (one wave per dst) ----------------
// KV layout: row s = 512 ushorts; lane ln's dwordx4 at s*512+ln*8 = {k0..k3, v0..v3}
// Chunked online softmax: 8 edges per iteration; prif folded into q; first chunk
// skips the rescale chain (l,a are zero -> bit-identical).
__global__ __launch_bounds__(256) void edge_agg_all(ushort* __restrict__ Qe0,
                                                    ushort* __restrict__ Qe1,
                                                    ushort* __restrict__ Qe2,
                                                    const ushort* __restrict__ KVa,
                                                    const ushort* __restrict__ KVp,
                                                    const int* __restrict__ offs,
                                                    const int* __restrict__ csr,
                                                    const void* __restrict__ pri) {
  int isbf = get_isbf(pri);
  int wv = threadIdx.x >> 6;
  int g = blockIdx.x * 4 + wv;
  if (g >= NTOT) return;
  int ln = threadIdx.x & 63;
  int h = ln >> 3;
  int d, pri_off, n_src;
  ushort* Q;
  const ushort* KV;
  if (g < NP) {
    d = g; Q = Qe0; KV = KVa; pri_off = 0; n_src = NA;
  } else if (g < 2 * NP) {
    d = g - NP; Q = Qe1; KV = KVp; pri_off = 8; n_src = NP;
  } else {
    d = g - 2 * NP; Q = Qe2; KV = KVp; pri_off = 16; n_src = NP;
  }
  float prif = ldf(pri, pri_off + h, isbf) * 0.17677669529663687f;  // 1/sqrt(32)
  ushort4 qu = *(const ushort4*)(Q + (size_t)d * 256 + ln * 4);
  float q0 = b2f(qu.x) * prif, q1 = b2f(qu.y) * prif;
  float q2 = b2f(qu.z) * prif, q3 = b2f(qu.w) * prif;
  float m = -1e30f, l = 0.f;
  float a0 = 0.f, a1 = 0.f, a2 = 0.f, a3 = 0.f;
  int e0 = __builtin_amdgcn_readfirstlane(offs[g]);
  int e1 = __builtin_amdgcn_readfirstlane(offs[g + 1]);
  if (e1 > e0 + 4096) e1 = e0 + 4096;  // firewall

  for (int e = e0; e < e1; e += 8) {
    int nv = e1 - e;
    nv = (nv > 8) ? 8 : nv;  // wave-uniform
    int4 kv[8];
    float sc[8];
#pragma unroll
    for (int i = 0; i < 8; i++) sc[i] = -1e30f;
    // issue all loads first: 8-deep memory pipeline
#pragma unroll
    for (int i = 0; i < 8; i++) {
      if (i < nv) {
        unsigned s = (unsigned)csr[e + i];   // scalar (e uniform)
        if (s >= (unsigned)n_src) s = 0;     // firewall
        kv[i] = *(const int4*)(KV + (size_t)s * 512 + ln * 8);
      }
    }
    // independent dot + reduce per edge
#pragma unroll
    for (int i = 0; i < 8; i++) {
      if (i < nv) {
        float p = q0 * b2f_lo(kv[i].x) + q1 * b2f_hi(kv[i].x) +
                  q2 * b2f_lo(kv[i].y) + q3 * b2f_hi(kv[i].y);
        p += __shfl_xor(p, 1);
        p += __shfl_xor(p, 2);
        p += __shfl_xor(p, 4);
        sc[i] = p;
      }
    }
    // one max-merge + one rescale per chunk (first chunk: l,a zero -> skip)
    float mc = fmaxf(fmaxf(fmaxf(sc[0], sc[1]), fmaxf(sc[2], sc[3])),
                     fmaxf(fmaxf(sc[4], sc[5]), fmaxf(sc[6], sc[7])));
    float mn = fmaxf(m, mc);
    if (e != e0) {
      float scale = __expf(m - mn);
      l *= scale; a0 *= scale; a1 *= scale; a2 *= scale; a3 *= scale;
    }
#pragma unroll
    for (int i = 0; i < 8; i++) {
      if (i < nv) {
        float wgt = __expf(sc[i] - mn);
        l += wgt;
        a0 += wgt * b2f_lo(kv[i].z);
        a1 += wgt * b2f_hi(kv[i].z);
        a2 += wgt * b2f_lo(kv[i].w);
        a3 += wgt * b2f_hi(kv[i].w);
      }
    }
    m = mn;
  }
  float inv = (l > 0.f) ? 1.f / l : 0.f;
  ushort4 o;
  o.x = f2b(a0 * inv);
  o.y = f2b(a1 * inv);
  o.z = f2b(a2 * inv);
  o.w = f2b(a3 * inv);
  *(ushort4*)(Q + (size_t)d * 256 + ln * 4) = o;  // in-place agg
}

// ---------------- launch ----------------
extern "C" void kernel_launch(void* const* d_in, const int* in_sizes, int n_in,
                              void* d_out, int out_size, void* d_ws, size_t ws_size,
                              hipStream_t stream) {
  (void)in_sizes; (void)n_in; (void)out_size; (void)ws_size;
  const void* h_a = d_in[0];
  const void* h_p = d_in[1];
  const void* k_w = d_in[2];
  const void* k_b = d_in[3];
  const void* q_w = d_in[4];
  const void* q_b = d_in[5];
  const void* v_w = d_in[6];
  const void* v_b = d_in[7];
  const void* a_w = d_in[8];
  const void* a_b = d_in[9];
  const void* ratt = d_in[10];
  const void* rmsg = d_in[11];
  const void* rpri = d_in[12];
  const void* skip = d_in[13];
  const int* src_w = (const int*)d_in[14];
  const int* dst_w = (const int*)d_in[15];
  const int* src_c = (const int*)d_in[16];
  const int* dst_c = (const int*)d_in[17];
  const int* src_b = (const int*)d_in[18];
  const int* dst_b = (const int*)d_in[19];

  char* w = (char*)d_ws;
  size_t ofs = 0;
  auto alloc = [&](size_t bytes) {
    char* p = w + ofs;
    ofs = (ofs + bytes + 255) & ~(size_t)255;
    return p;
  };
  ushort* Bp = (ushort*)alloc((size_t)1024 * 256 * 2);  // [kw1; vw1; qeff e0; qeff e1]
  ushort* Ba = (ushort*)alloc((size_t)768 * 256 * 2);   // [kw0; vw0; qeff e2]
  ushort* aeff = (ushort*)alloc((size_t)3 * 256 * 256 * 2);
  float* gb = (float*)alloc((size_t)7 * 256 * 4);
  int* cnt = (int*)alloc((size_t)NTOT * 4);
  int* offs = (int*)alloc((size_t)(NTOT + 1) * 4);
  int* bsum = (int*)alloc(64 * 4);
  int* ebase = (int*)alloc(64 * 4);
  int* cur = (int*)alloc((size_t)NTOT * 4);
  int* csr = (int*)alloc((size_t)3 * NE * 4);
  ushort* Ha = (ushort*)alloc((size_t)NA * DD * 2);    // bf16 h_author
  ushort* Hp = (ushort*)alloc((size_t)NP * DD * 2);    // bf16 h_paper
  ushort* KVa = (ushort*)alloc((size_t)NA * 512 * 2);  // interleaved K/V, author srcs
  ushort* KVp = (ushort*)alloc((size_t)NP * 512 * 2);  // interleaved K/V, paper srcs
  ushort* Qe0 = (ushort*)alloc((size_t)NP * DD * 2);
  ushort* Qe1 = (ushort*)alloc((size_t)NP * DD * 2);
  ushort* Qe2 = (ushort*)alloc((size_t)NA * DD * 2);
  ushort* agg0 = Qe0;  // in-place edge_agg
  ushort* agg1 = Qe1;
  ushort* agg2 = Qe2;

  hipMemsetAsync(cnt, 0, (size_t)NTOT * 4, stream);

  cvt_h<<<(2240000 + 255) / 256, 256, 0, stream>>>(h_a, h_p, Ha, Hp, rpri);
  prep<<<dim3(256, 7), 256, 0, stream>>>(q_w, a_w, k_w, v_w, k_b, v_b, q_b,
                                         ratt, rmsg, Bp, Ba, aeff, gb, rpri);

  // projections: single merged launch, XCD-aware (rt,job) decode
  GemmC4 cpp, cpa;
  cpp.c[0] = KVp; cpp.ilv[0] = 1;
  cpp.c[1] = KVp; cpp.ilv[1] = 2;
  cpp.c[2] = Qe0; cpp.ilv[2] = 0;
  cpp.c[3] = Qe1; cpp.ilv[3] = 0;
  cpa.c[0] = KVa; cpa.ilv[0] = 1;
  cpa.c[1] = KVa; cpa.ilv[1] = 2;
  cpa.c[2] = Qe2; cpa.ilv[2] = 0;
  cpa.c[3] = Qe2; cpa.ilv[3] = 0;  // unused
  gemm_proj<<<8 * 50 * 14, 256, 0, stream>>>(Hp, Ha, Bp, Ba, gb, cpp, cpa);

  // CSR build
  count_edges<<<(3 * NE + 255) / 256, 256, 0, stream>>>(dst_w, dst_c, dst_b, cnt);
  reduce_cnt<<<NBLK, 256, 0, stream>>>(cnt, bsum);
  scan_top<<<1, 64, 0, stream>>>(bsum, ebase);
  scan_final<<<NBLK, 256, 0, stream>>>(cnt, ebase, offs, cur);
  scatter_edges<<<(3 * NE + 255) / 256, 256, 0, stream>>>(src_w, dst_w, src_c, dst_c,
                                                          src_b, dst_b, cur, csr);

  // merged aggregation: one wave per joint dst bucket
  edge_agg_all<<<(NTOT + 3) / 4, 256, 0, stream>>>(Qe0, Qe1, Qe2, KVa, KVp,
                                                   offs, csr, rpri);

  // merged output GEMM (2-D grid): y<2 author, y>=2 paper
  out_gemm2<<<dim3((NP + 127) / 128, 4), 256, 0, stream>>>(
      agg2, aeff + 131072, agg0, aeff, agg1, aeff + 65536,
      a_b, h_a, h_p, skip, d_out, rpri);
}

// Round 9
// 541.589 us; speedup vs baseline: 1.4382x; 1.0765x over previous
//
#include <hip/hip_runtime.h>
#include <hip/hip_bf16.h>

#define NA 20000
#define NP 50000
#define NE 300000
#define DD 256
#define HH 8
#define NTOT (2 * NP + NA)           // 120000 joint dst buckets
#define NBLK ((NTOT + 2047) / 2048)  // 59 scan blocks
#define NRT 391                      // ceil(NP/128) row tiles

// phase0 block ranges
#define CVT_B 8750                   // ceil(2240000/256)
#define PREP_B 1792                  // 256 x 7
#define CNT_B 3516                   // ceil(900000/256)
// proj+scatter ranges
#define PROJ_B (8 * 50 * 14)         // 5600
#define SCAT_B 3516

typedef short bf16x8 __attribute__((ext_vector_type(8)));
typedef float f32x4 __attribute__((ext_vector_type(4)));

__device__ __forceinline__ float b2f(ushort u) {
  unsigned v = ((unsigned)u) << 16;
  float f;
  __builtin_memcpy(&f, &v, 4);
  return f;
}
__device__ __forceinline__ float b2f_lo(int u) {
  unsigned v = ((unsigned)u) << 16;
  float f;
  __builtin_memcpy(&f, &v, 4);
  return f;
}
__device__ __forceinline__ float b2f_hi(int u) {
  unsigned v = ((unsigned)u) & 0xffff0000u;
  float f;
  __builtin_memcpy(&f, &v, 4);
  return f;
}
__device__ __forceinline__ ushort f2b(float f) {
  unsigned u;
  __builtin_memcpy(&u, &f, 4);
  u = u + 0x7fffu + ((u >> 16) & 1u);
  return (ushort)(u >> 16);
}
__device__ __forceinline__ unsigned pk2(float lo, float hi) {
  return (unsigned)f2b(lo) | ((unsigned)f2b(hi) << 16);
}
// dual-dtype scalar load (isbf: 1 = bf16, 0 = fp32)
__device__ __forceinline__ float ldf(const void* p, int i, int isbf) {
  return isbf ? b2f(((const ushort*)p)[i]) : ((const float*)p)[i];
}
// rel_pri is all-ones: first u32 is 0x3F803F80 if bf16-packed, 0x3F800000 if fp32.
__device__ __forceinline__ int get_isbf(const void* rpri) {
  return ((const unsigned*)rpri)[0] == 0x3F803F80u;
}
// async global->LDS, 16B per lane; LDS dest must be wave-uniform base (+lane*16 implicit)
__device__ __forceinline__ void gload16(const void* g, void* l) {
  __builtin_amdgcn_global_load_lds(
      (const __attribute__((address_space(1))) void*)g,
      (__attribute__((address_space(3))) void*)l, 16, 0, 0);
}

// ---------------- phase0: cvt_h || prep (Qeff/Aeff/panels/biases) || count_edges ----------------
__global__ __launch_bounds__(256) void phase0(const void* __restrict__ ha,
                                              const void* __restrict__ hp,
                                              ushort* __restrict__ Ha,
                                              ushort* __restrict__ Hp,
                                              const void* __restrict__ q_w,
                                              const void* __restrict__ a_w,
                                              const void* __restrict__ k_w,
                                              const void* __restrict__ v_w,
                                              const void* __restrict__ k_b,
                                              const void* __restrict__ v_b,
                                              const void* __restrict__ q_b,
                                              const void* __restrict__ ratt,
                                              const void* __restrict__ rmsg,
                                              ushort* __restrict__ Bp,
                                              ushort* __restrict__ Ba,
                                              ushort* __restrict__ aeff,
                                              float* __restrict__ gb,
                                              const int* __restrict__ d0,
                                              const int* __restrict__ d1,
                                              const int* __restrict__ d2,
                                              int* __restrict__ cnt,
                                              const void* __restrict__ rpri) {
  const int b = blockIdx.x;
  const int c = threadIdx.x;
  const int isbf = get_isbf(rpri);
  if (b < CVT_B) {
    // ---- cvt_h: h_a / h_p -> bf16 (8 elems/thread) ----
    size_t t = (size_t)b * 256 + c;
    const size_t nA = (size_t)NA * 256 / 8;        // 640000
    const size_t nT = nA + (size_t)NP * 256 / 8;   // 2240000
    if (t >= nT) return;
    const void* src;
    ushort* dst;
    size_t o;
    if (t < nA) { src = ha; dst = Ha; o = t * 8; }
    else        { src = hp; dst = Hp; o = (t - nA) * 8; }
    if (isbf) {
      *(int4*)(dst + o) = *(const int4*)((const ushort*)src + o);
    } else {
      const float* f = (const float*)src + o;
      float4 x = *(const float4*)f;
      float4 y = *(const float4*)(f + 4);
      int4 v;
      v.x = (int)pk2(x.x, x.y); v.y = (int)pk2(x.z, x.w);
      v.z = (int)pk2(y.x, y.y); v.w = (int)pk2(y.z, y.w);
      *(int4*)(dst + o) = v;
    }
  } else if (b < CVT_B + PREP_B) {
    // ---- prep ----
    int pid = b - CVT_B;
    int y = pid >> 8;     // 0..6
    int r = pid & 255;
    if (y < 3) {
      int e = y;
      int nt = (e == 2) ? 0 : 1;
      int h = r >> 5, i = r & 31;
      int rb = ((e * HH + h) * 32 + i) * 32;
      int qb = nt * 65536 + (h * 32) * 256 + c;
      float s = 0.f;
#pragma unroll 8
      for (int j = 0; j < 32; j++) s += ldf(ratt, rb + j, isbf) * ldf(q_w, qb + j * 256, isbf);
      ushort* dst = (e == 2) ? (Ba + (size_t)(512 + r) * 256)
                             : (Bp + (size_t)(512 + e * 256 + r) * 256);
      dst[c] = f2b(s);
    } else if (y < 6) {
      int e = y - 3;
      int o = r;
      int nt = (e == 2) ? 0 : 1;
      int h = c >> 5, i = c & 31;
      int rb = ((e * HH + h) * 32 + i) * 32;
      int ab = nt * 65536 + o * 256 + h * 32;
      float s = 0.f;
#pragma unroll 8
      for (int j = 0; j < 32; j++) s += ldf(rmsg, rb + j, isbf) * ldf(a_w, ab + j, isbf);
      aeff[(e * 256 + o) * 256 + c] = f2b(s);
    } else if (r < 128) {
      // k_w/v_w -> bf16 panels (4 sections x 65536 elems, 8/thread)
      int t = r * 256 + c;  // 0..32767
      int sec = t >> 13;
      int o = (t & 8191) * 8;
      const void* src = (sec == 0 || sec == 2) ? k_w : v_w;
      size_t soff = (sec < 2) ? (size_t)(65536 + o) : (size_t)o;
      ushort* dst = (sec == 0) ? (Bp + o)
                  : (sec == 1) ? (Bp + 65536 + o)
                  : (sec == 2) ? (Ba + o)
                               : (Ba + 65536 + o);
      if (isbf) {
        *(int4*)dst = *(const int4*)((const ushort*)src + soff);
      } else {
        const float* f = (const float*)src + soff;
        float4 x = *(const float4*)f;
        float4 yy = *(const float4*)(f + 4);
        int4 v;
        v.x = (int)pk2(x.x, x.y); v.y = (int)pk2(x.z, x.w);
        v.z = (int)pk2(yy.x, yy.y); v.w = (int)pk2(yy.z, yy.w);
        *(int4*)dst = v;
      }
    } else if (r == 128) {
      gb[0 * 256 + c] = ldf(k_b, 256 + c, isbf);
      gb[1 * 256 + c] = ldf(v_b, 256 + c, isbf);
      gb[4 * 256 + c] = ldf(k_b, c, isbf);
      gb[5 * 256 + c] = ldf(v_b, c, isbf);
      int h = c >> 5, i = c & 31;
      for (int e = 0; e < 3; e++) {
        int ntp = (e == 2) ? 0 : 1;
        int rb = ((e * HH + h) * 32 + i) * 32;
        float s = 0.f;
        for (int j = 0; j < 32; j++)
          s += ldf(ratt, rb + j, isbf) * ldf(q_b, ntp * 256 + h * 32 + j, isbf);
        gb[(e == 2 ? 6 : (2 + e)) * 256 + c] = s;
      }
    }
  } else {
    // ---- count_edges ----
    int i = (b - CVT_B - PREP_B) * 256 + c;
    if (i >= 3 * NE) return;
    int et = (i >= 2 * NE) ? 2 : ((i >= NE) ? 1 : 0);
    int e = i - et * NE;
    const int* dd = (et == 0) ? d0 : ((et == 1) ? d1 : d2);
    int base = (et == 0) ? 0 : ((et == 1) ? NP : 2 * NP);
    atomicAdd(&cnt[base + dd[e]], 1);
  }
}

// ---------------- merged: gemm_proj (blocks < PROJ_B) || scatter_edges ----------------
// GEMM: operand-swapped MFMA (acc = mfma(B,A)) -> lane = one row x 4 consecutive cols
// -> vectorized ushort4 C stores. XCD-aware decode (14 jobs/row-tile on one XCD).
// ilv: 0 = plain [row][256]; 1 = K-half of interleaved KV[row][512]; 2 = V-half.
struct GemmC4 { ushort* c[4]; int ilv[4]; };

__global__ __launch_bounds__(256) void proj_scatter(const ushort* __restrict__ Hp,
                                                    const ushort* __restrict__ Ha,
                                                    const ushort* __restrict__ Bpp,
                                                    const ushort* __restrict__ Bap,
                                                    const float* __restrict__ gb,
                                                    GemmC4 cpp, GemmC4 cpa,
                                                    const int* __restrict__ s0,
                                                    const int* __restrict__ d0,
                                                    const int* __restrict__ s1,
                                                    const int* __restrict__ d1,
                                                    const int* __restrict__ s2,
                                                    const int* __restrict__ d2,
                                                    int* __restrict__ cur,
                                                    int* __restrict__ csr) {
  __shared__ __align__(16) ushort As[2][4096];  // [128][32] bf16, linear
  __shared__ __align__(16) ushort Bs[2][4096];
  const int bid = blockIdx.x;
  if (bid >= PROJ_B) {
    // ---- scatter_edges ----
    int i = (bid - PROJ_B) * 256 + threadIdx.x;
    if (i >= 3 * NE) return;
    int et = (i >= 2 * NE) ? 2 : ((i >= NE) ? 1 : 0);
    int e = i - et * NE;
    const int* ss = (et == 0) ? s0 : ((et == 1) ? s1 : s2);
    const int* dd = (et == 0) ? d0 : ((et == 1) ? d1 : d2);
    int base = (et == 0) ? 0 : ((et == 1) ? NP : 2 * NP);
    int pos = atomicAdd(&cur[base + dd[e]], 1);  // global position in joint CSR
    csr[pos] = ss[e];
    return;
  }
  // ---- gemm_proj ----
  const int xcd = bid & 7, seq = bid >> 3;
  const int rt = (seq / 14) * 8 + xcd;   // row tile: same rt x all jobs -> same XCD
  const int y = seq % 14;                // col-panel job
  if (rt >= NRT) return;
  const int isNP = (y < 8);
  const int M = isNP ? NP : NA;
  const int row0 = rt * 128;
  if (row0 >= M) return;
  const ushort* A = isNP ? Hp : Ha;
  const ushort* B = isNP ? Bpp : Bap;
  const float* gbias = isNP ? gb : (gb + 1024);
  const int col0 = (isNP ? y : (y - 8)) * 128;
  const GemmC4 cp = isNP ? cpp : cpa;
  ushort* C = cp.c[col0 >> 8];
  const int ilv = cp.ilv[col0 >> 8];
  const int ccol0 = col0 & 255;

  const int tid = threadIdx.x;
  const int ln = tid & 63, wv = tid >> 6;
  const int quad = ln >> 4, lr = ln & 15;
  const int wr = wv >> 1, wc = wv & 1;  // 2x2 wave grid over 128x128

  f32x4 acc[4][4];
#pragma unroll
  for (int m = 0; m < 4; m++)
#pragma unroll
    for (int n = 0; n < 4; n++) acc[m][n] = (f32x4){0.f, 0.f, 0.f, 0.f};

  // staging chunk map: thread t stages 16B at LDS ushort t*8 -> row t>>2, seg t&3
  const int r0 = tid >> 2, seg = tid & 3;
  const int r1 = 64 + r0;
  int ar0 = row0 + r0; if (ar0 >= M) ar0 = M - 1;  // clamp; guarded at store
  int ar1 = row0 + r1; if (ar1 >= M) ar1 = M - 1;
  const ushort* gA0 = A + ((size_t)ar0 * 256 + seg * 8);
  const ushort* gA1 = A + ((size_t)ar1 * 256 + seg * 8);
  const ushort* gB0 = B + ((size_t)(col0 + r0) * 256 + seg * 8);
  const ushort* gB1 = B + ((size_t)(col0 + r1) * 256 + seg * 8);
  const int lbase = (tid & 192) * 8;  // wave-uniform LDS ushort offset

  auto stage = [&](int kb, int buf) {
    gload16(gA0 + kb * 32, As[buf] + lbase);
    gload16(gA1 + kb * 32, As[buf] + 2048 + lbase);
    gload16(gB0 + kb * 32, Bs[buf] + lbase);
    gload16(gB1 + kb * 32, Bs[buf] + 2048 + lbase);
  };

  stage(0, 0);
  __syncthreads();
  for (int kb = 0; kb < 8; kb++) {
    const int cur_ = kb & 1;
    if (kb < 7) stage(kb + 1, cur_ ^ 1);
    bf16x8 af[4], bfr[4];
#pragma unroll
    for (int m = 0; m < 4; m++)
      af[m] = *(const bf16x8*)&As[cur_][(wr * 64 + m * 16 + lr) * 32 + quad * 8];
#pragma unroll
    for (int n = 0; n < 4; n++)
      bfr[n] = *(const bf16x8*)&Bs[cur_][(wc * 64 + n * 16 + lr) * 32 + quad * 8];
    // swapped operands: D^T fragments -> lane = (row: m*16+lr, cols: n*16+quad*4+r)
#pragma unroll
    for (int m = 0; m < 4; m++)
#pragma unroll
      for (int n = 0; n < 4; n++)
        acc[m][n] = __builtin_amdgcn_mfma_f32_16x16x32_bf16(bfr[n], af[m], acc[m][n], 0, 0, 0);
    __syncthreads();  // drains prefetch vmcnt + protects buffer reuse
  }

  const int voff = (ilv == 2) ? 4 : 0;
#pragma unroll
  for (int m = 0; m < 4; m++) {
    int row = row0 + wr * 64 + m * 16 + lr;
    if (row >= M) continue;
#pragma unroll
    for (int n = 0; n < 4; n++) {
      int ccol = ccol0 + wc * 64 + n * 16 + quad * 4;  // 4-aligned
      int gcol = col0 + wc * 64 + n * 16 + quad * 4;
      float4 bv = *(const float4*)(gbias + gcol);
      ushort4 o;
      o.x = f2b(acc[m][n][0] + bv.x);
      o.y = f2b(acc[m][n][1] + bv.y);
      o.z = f2b(acc[m][n][2] + bv.z);
      o.w = f2b(acc[m][n][3] + bv.w);
      size_t cidx = ilv ? ((size_t)row * 512 + (size_t)(ccol >> 2) * 8 + voff)
                        : ((size_t)row * 256 + ccol);
      *(ushort4*)(C + cidx) = o;  // 8B-aligned in all cases
    }
  }
}

// out = alpha*(A0@B0^T [+A1@B1^T] + ab) + (1-alpha)*h   (A,B internal bf16)
// 2-D grid. Operand-swapped MFMA -> float4/ushort4 epilogue.
// job y<2 -> author (N=256, 1 group); y>=2 -> paper (2 groups)
__global__ __launch_bounds__(256) void out_gemm2(const ushort* __restrict__ Aa,
                                                 const ushort* __restrict__ Ba_,
                                                 const ushort* __restrict__ Ap0,
                                                 const ushort* __restrict__ Bp0,
                                                 const ushort* __restrict__ Ap1,
                                                 const ushort* __restrict__ Bp1,
                                                 const void* __restrict__ ab,
                                                 const void* __restrict__ h_a,
                                                 const void* __restrict__ h_p,
                                                 const void* __restrict__ skipv,
                                                 void* __restrict__ out,
                                                 const void* __restrict__ rpri) {
  const int y = blockIdx.y;
  const int isA = (y < 2);
  const int M = isA ? NA : NP;
  const int row0 = blockIdx.x * 128;
  if (row0 >= M) return;
  const ushort* A0 = isA ? Aa : Ap0;
  const ushort* B0 = isA ? Ba_ : Bp0;
  const ushort* A1 = isA ? nullptr : Ap1;
  const ushort* B1 = isA ? nullptr : Bp1;
  const int ab_off = isA ? 0 : 256;
  const void* h = isA ? h_a : h_p;
  const int skipidx = isA ? 0 : 1;
  const size_t out_off = isA ? 0 : (size_t)NA * DD;
  const int col0 = (isA ? y : (y - 2)) * 128;

  const int isbf = get_isbf(rpri);
  __shared__ __align__(16) ushort As[2][4096];
  __shared__ __align__(16) ushort Bs[2][4096];
  const int tid = threadIdx.x;
  const int ln = tid & 63, wv = tid >> 6;
  const int quad = ln >> 4, lr = ln & 15;
  const int wr = wv >> 1, wc = wv & 1;

  f32x4 acc[4][4];
#pragma unroll
  for (int m = 0; m < 4; m++)
#pragma unroll
    for (int n = 0; n < 4; n++) acc[m][n] = (f32x4){0.f, 0.f, 0.f, 0.f};

  const int r0 = tid >> 2, seg = tid & 3;
  const int r1 = 64 + r0;
  int ar0 = row0 + r0; if (ar0 >= M) ar0 = M - 1;
  int ar1 = row0 + r1; if (ar1 >= M) ar1 = M - 1;
  const int lbase = (tid & 192) * 8;

  const int nsteps = (A1 != nullptr) ? 16 : 8;
  auto stage = [&](int s, int buf) {
    int g = s >> 3, kb = s & 7;
    const ushort* A = g ? A1 : A0;
    const ushort* B = g ? B1 : B0;
    gload16(A + (size_t)ar0 * 256 + seg * 8 + kb * 32, As[buf] + lbase);
    gload16(A + (size_t)ar1 * 256 + seg * 8 + kb * 32, As[buf] + 2048 + lbase);
    gload16(B + (size_t)(col0 + r0) * 256 + seg * 8 + kb * 32, Bs[buf] + lbase);
    gload16(B + (size_t)(col0 + r1) * 256 + seg * 8 + kb * 32, Bs[buf] + 2048 + lbase);
  };

  stage(0, 0);
  __syncthreads();
  for (int s = 0; s < nsteps; s++) {
    const int cur_ = s & 1;
    if (s + 1 < nsteps) stage(s + 1, cur_ ^ 1);
    bf16x8 af[4], bfr[4];
#pragma unroll
    for (int m = 0; m < 4; m++)
      af[m] = *(const bf16x8*)&As[cur_][(wr * 64 + m * 16 + lr) * 32 + quad * 8];
#pragma unroll
    for (int n = 0; n < 4; n++)
      bfr[n] = *(const bf16x8*)&Bs[cur_][(wc * 64 + n * 16 + lr) * 32 + quad * 8];
#pragma unroll
    for (int m = 0; m < 4; m++)
#pragma unroll
      for (int n = 0; n < 4; n++)
        acc[m][n] = __builtin_amdgcn_mfma_f32_16x16x32_bf16(bfr[n], af[m], acc[m][n], 0, 0, 0);
    __syncthreads();
  }

  float alpha = 1.f / (1.f + __expf(-ldf(skipv, skipidx, isbf)));
  float beta = 1.f - alpha;
#pragma unroll
  for (int m = 0; m < 4; m++) {
    int row = row0 + wr * 64 + m * 16 + lr;
    if (row >= M) continue;
#pragma unroll
    for (int n = 0; n < 4; n++) {
      int col = col0 + wc * 64 + n * 16 + quad * 4;  // 4-aligned
      size_t base = (size_t)row * 256 + col;
      float t0 = acc[m][n][0] + ldf(ab, ab_off + col + 0, isbf);
      float t1 = acc[m][n][1] + ldf(ab, ab_off + col + 1, isbf);
      float t2 = acc[m][n][2] + ldf(ab, ab_off + col + 2, isbf);
      float t3 = acc[m][n][3] + ldf(ab, ab_off + col + 3, isbf);
      if (isbf) {
        ushort4 hu = *(const ushort4*)((const ushort*)h + base);
        ushort4 o;
        o.x = f2b(alpha * t0 + beta * b2f(hu.x));
        o.y = f2b(alpha * t1 + beta * b2f(hu.y));
        o.z = f2b(alpha * t2 + beta * b2f(hu.z));
        o.w = f2b(alpha * t3 + beta * b2f(hu.w));
        *(ushort4*)((ushort*)out + out_off + base) = o;
      } else {
        float4 hf = *(const float4*)((const float*)h + base);
        float4 o;
        o.x = alpha * t0 + beta * hf.x;
        o.y = alpha * t1 + beta * hf.y;
        o.z = alpha * t2 + beta * hf.z;
        o.w = alpha * t3 + beta * hf.w;
        *(float4*)((float*)out + out_off + base) = o;
      }
    }
  }
}

// ---------------- CSR scan kernels ----------------
__global__ __launch_bounds__(256) void reduce_cnt(const int* __restrict__ cnt,
                                                  int* __restrict__ bsum) {
  __shared__ int red[256];
  int t = threadIdx.x;
  int base = blockIdx.x * 2048 + t * 8;
  int s = 0;
#pragma unroll
  for (int j = 0; j < 8; j++) s += (base + j < NTOT) ? cnt[base + j] : 0;
  red[t] = s;
  __syncthreads();
  for (int o = 128; o > 0; o >>= 1) {
    if (t < o) red[t] += red[t + o];
    __syncthreads();
  }
  if (t == 0) bsum[blockIdx.x] = red[0];
}

__global__ __launch_bounds__(64) void scan_top(const int* __restrict__ bsum,
                                               int* __restrict__ ebase) {
  __shared__ int ts[64];
  int t = threadIdx.x;
  int v = (t < NBLK) ? bsum[t] : 0;
  ts[t] = v;
  __syncthreads();
  for (int o = 1; o < 64; o <<= 1) {
    int x = (t >= o) ? ts[t - o] : 0;
    __syncthreads();
    ts[t] += x;
    __syncthreads();
  }
  if (t < NBLK) ebase[t] = ts[t] - v;  // exclusive
}

__global__ __launch_bounds__(256) void scan_final(const int* __restrict__ cnt,
                                                  const int* __restrict__ ebase,
                                                  int* __restrict__ offs,
                                                  int* __restrict__ cur) {
  __shared__ int ts[256];
  int t = threadIdx.x;
  int base = blockIdx.x * 2048 + t * 8;
  int v[8];
  int s = 0;
#pragma unroll
  for (int j = 0; j < 8; j++) {
    int x = (base + j < NTOT) ? cnt[base + j] : 0;
    v[j] = s;
    s += x;
  }
  ts[t] = s;
  __syncthreads();
  for (int o = 1; o < 256; o <<= 1) {
    int x = (t >= o) ? ts[t - o] : 0;
    __syncthreads();
    ts[t] += x;
    __syncthreads();
  }
  int tb = ebase[blockIdx.x] + ts[t] - s;
#pragma unroll
  for (int j = 0; j < 8; j++) {
    int i = base + j;
    if (i < NTOT) {
      int o2 = tb + v[j];
      offs[i] = o2;
      cur[i] = o2;
    }
  }
  if (blockIdx.x == 0 && t == 0) offs[NTOT] = 3 * NE;
}

// ---------------- merged per-dst online-softmax aggregation (one wave per dst) ----------------
// KV layout: row s = 512 ushorts; lane ln's dwordx4 at s*512+ln*8 = {k0..k3, v0..v3}
// Chunked online softmax: 8 edges/iter, UNCONDITIONAL clamped loads (padded slots
// get sc=-1e30 -> exp underflows to exact 0 -> bit-identical); prif folded into q;
// first chunk skips the rescale chain.
__global__ __launch_bounds__(256) void edge_agg_all(ushort* __restrict__ Qe0,
                                                    ushort* __restrict__ Qe1,
                                                    ushort* __restrict__ Qe2,
                                                    const ushort* __restrict__ KVa,
                                                    const ushort* __restrict__ KVp,
                                                    const int* __restrict__ offs,
                                                    const int* __restrict__ csr,
                                                    const void* __restrict__ pri) {
  int isbf = get_isbf(pri);
  int wv = threadIdx.x >> 6;
  int g = blockIdx.x * 4 + wv;
  if (g >= NTOT) return;
  int ln = threadIdx.x & 63;
  int h = ln >> 3;
  int d, pri_off, n_src;
  ushort* Q;
  const ushort* KV;
  if (g < NP) {
    d = g; Q = Qe0; KV = KVa; pri_off = 0; n_src = NA;
  } else if (g < 2 * NP) {
    d = g - NP; Q = Qe1; KV = KVp; pri_off = 8; n_src = NP;
  } else {
    d = g - 2 * NP; Q = Qe2; KV = KVp; pri_off = 16; n_src = NP;
  }
  float prif = ldf(pri, pri_off + h, isbf) * 0.17677669529663687f;  // 1/sqrt(32)
  ushort4 qu = *(const ushort4*)(Q + (size_t)d * 256 + ln * 4);
  float q0 = b2f(qu.x) * prif, q1 = b2f(qu.y) * prif;
  float q2 = b2f(qu.z) * prif, q3 = b2f(qu.w) * prif;
  float m = -1e30f, l = 0.f;
  float a0 = 0.f, a1 = 0.f, a2 = 0.f, a3 = 0.f;
  int e0 = __builtin_amdgcn_readfirstlane(offs[g]);
  int e1 = __builtin_amdgcn_readfirstlane(offs[g + 1]);
  if (e1 > e0 + 4096) e1 = e0 + 4096;  // firewall
  const int elast = e1 - 1;

  for (int e = e0; e < e1; e += 8) {
    int nv = e1 - e;
    nv = (nv > 8) ? 8 : nv;  // wave-uniform
    int4 kv[8];
    float sc[8];
    // unconditional clamped loads: 8-deep memory pipeline, no exec-mask churn
#pragma unroll
    for (int i = 0; i < 8; i++) {
      int idx = e + i;
      idx = (idx > elast) ? elast : idx;
      unsigned s = (unsigned)__builtin_amdgcn_readfirstlane(csr[idx]);  // scalar
      if (s >= (unsigned)n_src) s = 0;  // firewall
      kv[i] = *(const int4*)(KV + (size_t)s * 512 + ln * 8);
    }
    // independent dot + reduce per edge; padded slots -> -1e30
#pragma unroll
    for (int i = 0; i < 8; i++) {
      float p = q0 * b2f_lo(kv[i].x) + q1 * b2f_hi(kv[i].x) +
                q2 * b2f_lo(kv[i].y) + q3 * b2f_hi(kv[i].y);
      p += __shfl_xor(p, 1);
      p += __shfl_xor(p, 2);
      p += __shfl_xor(p, 4);
      sc[i] = (i < nv) ? p : -1e30f;
    }
    // one max-merge + one rescale per chunk (first chunk: l,a zero -> skip)
    float mc = fmaxf(fmaxf(fmaxf(sc[0], sc[1]), fmaxf(sc[2], sc[3])),
                     fmaxf(fmaxf(sc[4], sc[5]), fmaxf(sc[6], sc[7])));
    float mn = fmaxf(m, mc);
    if (e != e0) {
      float scale = __expf(m - mn);
      l *= scale; a0 *= scale; a1 *= scale; a2 *= scale; a3 *= scale;
    }
    // unconditional accumulate: padded wgt = exp(-1e30 - mn) = exact 0
#pragma unroll
    for (int i = 0; i < 8; i++) {
      float wgt = __expf(sc[i] - mn);
      l += wgt;
      a0 += wgt * b2f_lo(kv[i].z);
      a1 += wgt * b2f_hi(kv[i].z);
      a2 += wgt * b2f_lo(kv[i].w);
      a3 += wgt * b2f_hi(kv[i].w);
    }
    m = mn;
  }
  float inv = (l > 0.f) ? 1.f / l : 0.f;
  ushort4 o;
  o.x = f2b(a0 * inv);
  o.y = f2b(a1 * inv);
  o.z = f2b(a2 * inv);
  o.w = f2b(a3 * inv);
  *(ushort4*)(Q + (size_t)d * 256 + ln * 4) = o;  // in-place agg
}

// ---------------- launch ----------------
extern "C" void kernel_launch(void* const* d_in, const int* in_sizes, int n_in,
                              void* d_out, int out_size, void* d_ws, size_t ws_size,
                              hipStream_t stream) {
  (void)in_sizes; (void)n_in; (void)out_size; (void)ws_size;
  const void* h_a = d_in[0];
  const void* h_p = d_in[1];
  const void* k_w = d_in[2];
  const void* k_b = d_in[3];
  const void* q_w = d_in[4];
  const void* q_b = d_in[5];
  const void* v_w = d_in[6];
  const void* v_b = d_in[7];
  const void* a_w = d_in[8];
  const void* a_b = d_in[9];
  const void* ratt = d_in[10];
  const void* rmsg = d_in[11];
  const void* rpri = d_in[12];
  const void* skip = d_in[13];
  const int* src_w = (const int*)d_in[14];
  const int* dst_w = (const int*)d_in[15];
  const int* src_c = (const int*)d_in[16];
  const int* dst_c = (const int*)d_in[17];
  const int* src_b = (const int*)d_in[18];
  const int* dst_b = (const int*)d_in[19];

  char* w = (char*)d_ws;
  size_t ofs = 0;
  auto alloc = [&](size_t bytes) {
    char* p = w + ofs;
    ofs = (ofs + bytes + 255) & ~(size_t)255;
    return p;
  };
  ushort* Bp = (ushort*)alloc((size_t)1024 * 256 * 2);  // [kw1; vw1; qeff e0; qeff e1]
  ushort* Ba = (ushort*)alloc((size_t)768 * 256 * 2);   // [kw0; vw0; qeff e2]
  ushort* aeff = (ushort*)alloc((size_t)3 * 256 * 256 * 2);
  float* gb = (float*)alloc((size_t)7 * 256 * 4);
  int* cnt = (int*)alloc((size_t)NTOT * 4);
  int* offs = (int*)alloc((size_t)(NTOT + 1) * 4);
  int* bsum = (int*)alloc(64 * 4);
  int* ebase = (int*)alloc(64 * 4);
  int* cur = (int*)alloc((size_t)NTOT * 4);
  int* csr = (int*)alloc((size_t)3 * NE * 4);
  ushort* Ha = (ushort*)alloc((size_t)NA * DD * 2);    // bf16 h_author
  ushort* Hp = (ushort*)alloc((size_t)NP * DD * 2);    // bf16 h_paper
  ushort* KVa = (ushort*)alloc((size_t)NA * 512 * 2);  // interleaved K/V, author srcs
  ushort* KVp = (ushort*)alloc((size_t)NP * 512 * 2);  // interleaved K/V, paper srcs
  ushort* Qe0 = (ushort*)alloc((size_t)NP * DD * 2);
  ushort* Qe1 = (ushort*)alloc((size_t)NP * DD * 2);
  ushort* Qe2 = (ushort*)alloc((size_t)NA * DD * 2);
  ushort* agg0 = Qe0;  // in-place edge_agg
  ushort* agg1 = Qe1;
  ushort* agg2 = Qe2;

  hipMemsetAsync(cnt, 0, (size_t)NTOT * 4, stream);

  // phase0: cvt_h || prep || count_edges (all mutually independent)
  phase0<<<CVT_B + PREP_B + CNT_B, 256, 0, stream>>>(
      h_a, h_p, Ha, Hp, q_w, a_w, k_w, v_w, k_b, v_b, q_b, ratt, rmsg,
      Bp, Ba, aeff, gb, dst_w, dst_c, dst_b, cnt, rpri);

  // CSR scan chain
  reduce_cnt<<<NBLK, 256, 0, stream>>>(cnt, bsum);
  scan_top<<<1, 64, 0, stream>>>(bsum, ebase);
  scan_final<<<NBLK, 256, 0, stream>>>(cnt, ebase, offs, cur);

  // projections || scatter (mutually independent; both ready after scan_final/prep)
  GemmC4 cpp, cpa;
  cpp.c[0] = KVp; cpp.ilv[0] = 1;
  cpp.c[1] = KVp; cpp.ilv[1] = 2;
  cpp.c[2] = Qe0; cpp.ilv[2] = 0;
  cpp.c[3] = Qe1; cpp.ilv[3] = 0;
  cpa.c[0] = KVa; cpa.ilv[0] = 1;
  cpa.c[1] = KVa; cpa.ilv[1] = 2;
  cpa.c[2] = Qe2; cpa.ilv[2] = 0;
  cpa.c[3] = Qe2; cpa.ilv[3] = 0;  // unused
  proj_scatter<<<PROJ_B + SCAT_B, 256, 0, stream>>>(
      Hp, Ha, Bp, Ba, gb, cpp, cpa,
      src_w, dst_w, src_c, dst_c, src_b, dst_b, cur, csr);

  // merged aggregation: one wave per joint dst bucket
  edge_agg_all<<<(NTOT + 3) / 4, 256, 0, stream>>>(Qe0, Qe1, Qe2, KVa, KVp,
                                                   offs, csr, rpri);

  // merged output GEMM (2-D grid): y<2 author, y>=2 paper
  out_gemm2<<<dim3((NP + 127) / 128, 4), 256, 0, stream>>>(
      agg2, aeff + 131072, agg0, aeff, agg1, aeff + 65536,
      a_b, h_a, h_p, skip, d_out, rpri);
}

// Round 10
// 532.300 us; speedup vs baseline: 1.4633x; 1.0175x over previous
//
#include <hip/hip_runtime.h>
#include <hip/hip_bf16.h>

#define NA 20000
#define NP 50000
#define NE 300000
#define DD 256
#define HH 8
#define NTOT (2 * NP + NA)           // 120000 joint dst buckets
#define NBLK ((NTOT + 2047) / 2048)  // 59 scan blocks
#define NRT 391                      // ceil(NP/128) row tiles

// phase0 block ranges
#define CVT_B 8750                   // ceil(2240000/256)
#define PREP_B 1792                  // 256 x 7
#define CNT_B 3516                   // ceil(900000/256)
// proj+scatter ranges
#define PROJ_B (8 * 50 * 14)         // 5600
#define SCAT_B 3516

typedef short bf16x8 __attribute__((ext_vector_type(8)));
typedef float f32x4 __attribute__((ext_vector_type(4)));

__device__ __forceinline__ float b2f(ushort u) {
  unsigned v = ((unsigned)u) << 16;
  float f;
  __builtin_memcpy(&f, &v, 4);
  return f;
}
__device__ __forceinline__ float b2f_lo(int u) {
  unsigned v = ((unsigned)u) << 16;
  float f;
  __builtin_memcpy(&f, &v, 4);
  return f;
}
__device__ __forceinline__ float b2f_hi(int u) {
  unsigned v = ((unsigned)u) & 0xffff0000u;
  float f;
  __builtin_memcpy(&f, &v, 4);
  return f;
}
__device__ __forceinline__ ushort f2b(float f) {
  unsigned u;
  __builtin_memcpy(&u, &f, 4);
  u = u + 0x7fffu + ((u >> 16) & 1u);
  return (ushort)(u >> 16);
}
__device__ __forceinline__ unsigned pk2(float lo, float hi) {
  return (unsigned)f2b(lo) | ((unsigned)f2b(hi) << 16);
}
// dual-dtype scalar load (isbf: 1 = bf16, 0 = fp32)
__device__ __forceinline__ float ldf(const void* p, int i, int isbf) {
  return isbf ? b2f(((const ushort*)p)[i]) : ((const float*)p)[i];
}
// rel_pri is all-ones: first u32 is 0x3F803F80 if bf16-packed, 0x3F800000 if fp32.
__device__ __forceinline__ int get_isbf(const void* rpri) {
  return ((const unsigned*)rpri)[0] == 0x3F803F80u;
}
// async global->LDS, 16B per lane; LDS dest must be wave-uniform base (+lane*16 implicit)
__device__ __forceinline__ void gload16(const void* g, void* l) {
  __builtin_amdgcn_global_load_lds(
      (const __attribute__((address_space(1))) void*)g,
      (__attribute__((address_space(3))) void*)l, 16, 0, 0);
}

// ---------------- phase0: cvt_h || prep (Qeff/Aeff/panels/biases) || count_edges ----------------
__global__ __launch_bounds__(256) void phase0(const void* __restrict__ ha,
                                              const void* __restrict__ hp,
                                              ushort* __restrict__ Ha,
                                              ushort* __restrict__ Hp,
                                              const void* __restrict__ q_w,
                                              const void* __restrict__ a_w,
                                              const void* __restrict__ k_w,
                                              const void* __restrict__ v_w,
                                              const void* __restrict__ k_b,
                                              const void* __restrict__ v_b,
                                              const void* __restrict__ q_b,
                                              const void* __restrict__ ratt,
                                              const void* __restrict__ rmsg,
                                              ushort* __restrict__ Bp,
                                              ushort* __restrict__ Ba,
                                              ushort* __restrict__ aeff,
                                              float* __restrict__ gb,
                                              const int* __restrict__ d0,
                                              const int* __restrict__ d1,
                                              const int* __restrict__ d2,
                                              int* __restrict__ cnt,
                                              const void* __restrict__ rpri) {
  const int b = blockIdx.x;
  const int c = threadIdx.x;
  const int isbf = get_isbf(rpri);
  if (b < CVT_B) {
    // ---- cvt_h: h_a / h_p -> bf16 (8 elems/thread) ----
    size_t t = (size_t)b * 256 + c;
    const size_t nA = (size_t)NA * 256 / 8;        // 640000
    const size_t nT = nA + (size_t)NP * 256 / 8;   // 2240000
    if (t >= nT) return;
    const void* src;
    ushort* dst;
    size_t o;
    if (t < nA) { src = ha; dst = Ha; o = t * 8; }
    else        { src = hp; dst = Hp; o = (t - nA) * 8; }
    if (isbf) {
      *(int4*)(dst + o) = *(const int4*)((const ushort*)src + o);
    } else {
      const float* f = (const float*)src + o;
      float4 x = *(const float4*)f;
      float4 y = *(const float4*)(f + 4);
      int4 v;
      v.x = (int)pk2(x.x, x.y); v.y = (int)pk2(x.z, x.w);
      v.z = (int)pk2(y.x, y.y); v.w = (int)pk2(y.z, y.w);
      *(int4*)(dst + o) = v;
    }
  } else if (b < CVT_B + PREP_B) {
    // ---- prep ----
    int pid = b - CVT_B;
    int y = pid >> 8;     // 0..6
    int r = pid & 255;
    if (y < 3) {
      int e = y;
      int nt = (e == 2) ? 0 : 1;
      int h = r >> 5, i = r & 31;
      int rb = ((e * HH + h) * 32 + i) * 32;
      int qb = nt * 65536 + (h * 32) * 256 + c;
      float s = 0.f;
#pragma unroll 8
      for (int j = 0; j < 32; j++) s += ldf(ratt, rb + j, isbf) * ldf(q_w, qb + j * 256, isbf);
      ushort* dst = (e == 2) ? (Ba + (size_t)(512 + r) * 256)
                             : (Bp + (size_t)(512 + e * 256 + r) * 256);
      dst[c] = f2b(s);
    } else if (y < 6) {
      int e = y - 3;
      int o = r;
      int nt = (e == 2) ? 0 : 1;
      int h = c >> 5, i = c & 31;
      int rb = ((e * HH + h) * 32 + i) * 32;
      int ab = nt * 65536 + o * 256 + h * 32;
      float s = 0.f;
#pragma unroll 8
      for (int j = 0; j < 32; j++) s += ldf(rmsg, rb + j, isbf) * ldf(a_w, ab + j, isbf);
      aeff[(e * 256 + o) * 256 + c] = f2b(s);
    } else if (r < 128) {
      // k_w/v_w -> bf16 panels (4 sections x 65536 elems, 8/thread)
      int t = r * 256 + c;  // 0..32767
      int sec = t >> 13;
      int o = (t & 8191) * 8;
      const void* src = (sec == 0 || sec == 2) ? k_w : v_w;
      size_t soff = (sec < 2) ? (size_t)(65536 + o) : (size_t)o;
      ushort* dst = (sec == 0) ? (Bp + o)
                  : (sec == 1) ? (Bp + 65536 + o)
                  : (sec == 2) ? (Ba + o)
                               : (Ba + 65536 + o);
      if (isbf) {
        *(int4*)dst = *(const int4*)((const ushort*)src + soff);
      } else {
        const float* f = (const float*)src + soff;
        float4 x = *(const float4*)f;
        float4 yy = *(const float4*)(f + 4);
        int4 v;
        v.x = (int)pk2(x.x, x.y); v.y = (int)pk2(x.z, x.w);
        v.z = (int)pk2(yy.x, yy.y); v.w = (int)pk2(yy.z, yy.w);
        *(int4*)dst = v;
      }
    } else if (r == 128) {
      gb[0 * 256 + c] = ldf(k_b, 256 + c, isbf);
      gb[1 * 256 + c] = ldf(v_b, 256 + c, isbf);
      gb[4 * 256 + c] = ldf(k_b, c, isbf);
      gb[5 * 256 + c] = ldf(v_b, c, isbf);
      int h = c >> 5, i = c & 31;
      for (int e = 0; e < 3; e++) {
        int ntp = (e == 2) ? 0 : 1;
        int rb = ((e * HH + h) * 32 + i) * 32;
        float s = 0.f;
        for (int j = 0; j < 32; j++)
          s += ldf(ratt, rb + j, isbf) * ldf(q_b, ntp * 256 + h * 32 + j, isbf);
        gb[(e == 2 ? 6 : (2 + e)) * 256 + c] = s;
      }
    }
  } else {
    // ---- count_edges ----
    int i = (b - CVT_B - PREP_B) * 256 + c;
    if (i >= 3 * NE) return;
    int et = (i >= 2 * NE) ? 2 : ((i >= NE) ? 1 : 0);
    int e = i - et * NE;
    const int* dd = (et == 0) ? d0 : ((et == 1) ? d1 : d2);
    int base = (et == 0) ? 0 : ((et == 1) ? NP : 2 * NP);
    atomicAdd(&cnt[base + dd[e]], 1);
  }
}

// ---------------- merged: gemm_proj (blocks < PROJ_B) || scatter_edges ----------------
// GEMM: operand-swapped MFMA (acc = mfma(B,A)) -> lane = one row x 4 consecutive cols.
// K/V-PAIRED jobs: job covers K cols c0..c0+63 AND V cols c0..c0+63 -> the same
// block writes both 8B halves of each 16B KV unit (full-line write coalescing).
// 3-buffer pipeline with counted vmcnt(4) + raw s_barrier: the barrier drains only
// the NEXT tile's loads, never the newly issued batch.
// XCD-aware decode: 14 jobs/row-tile on one XCD -> A row-tile L2 reuse.
// NP jobs (y<8): y<4 pair(c0=y*64); y=4,5 Qe0; y=6,7 Qe1.
// NA jobs (y>=8): yy=y-8; yy<4 pair; yy=4,5 Qe2.
__global__ __launch_bounds__(256) void proj_scatter(const ushort* __restrict__ Hp,
                                                    const ushort* __restrict__ Ha,
                                                    const ushort* __restrict__ Bpp,
                                                    const ushort* __restrict__ Bap,
                                                    const float* __restrict__ gb,
                                                    ushort* __restrict__ KVp,
                                                    ushort* __restrict__ KVa,
                                                    ushort* __restrict__ Qe0,
                                                    ushort* __restrict__ Qe1,
                                                    ushort* __restrict__ Qe2,
                                                    const int* __restrict__ s0,
                                                    const int* __restrict__ d0,
                                                    const int* __restrict__ s1,
                                                    const int* __restrict__ d1,
                                                    const int* __restrict__ s2,
                                                    const int* __restrict__ d2,
                                                    int* __restrict__ cur,
                                                    int* __restrict__ csr) {
  __shared__ __align__(16) ushort As[3][4096];  // [128][32] bf16, linear
  __shared__ __align__(16) ushort Bs[3][4096];
  const int bid = blockIdx.x;
  if (bid >= PROJ_B) {
    // ---- scatter_edges ----
    int i = (bid - PROJ_B) * 256 + threadIdx.x;
    if (i >= 3 * NE) return;
    int et = (i >= 2 * NE) ? 2 : ((i >= NE) ? 1 : 0);
    int e = i - et * NE;
    const int* ss = (et == 0) ? s0 : ((et == 1) ? s1 : s2);
    const int* dd = (et == 0) ? d0 : ((et == 1) ? d1 : d2);
    int base = (et == 0) ? 0 : ((et == 1) ? NP : 2 * NP);
    int pos = atomicAdd(&cur[base + dd[e]], 1);  // global position in joint CSR
    csr[pos] = ss[e];
    return;
  }
  // ---- gemm_proj ----
  const int xcd = bid & 7, seq = bid >> 3;
  const int rt = (seq / 14) * 8 + xcd;   // row tile: same rt x all jobs -> same XCD
  const int y = seq % 14;                // col-panel job
  if (rt >= NRT) return;
  const int isNP = (y < 8);
  const int M = isNP ? NP : NA;
  const int row0 = rt * 128;
  if (row0 >= M) return;
  const ushort* A = isNP ? Hp : Ha;
  const ushort* B = isNP ? Bpp : Bap;
  const float* gbias = isNP ? gb : (gb + 1024);
  const int yy = isNP ? y : (y - 8);

  int pair, c0 = 0, b0, b64, cbias0, cbias64, qcol0 = 0;
  ushort* Cd;
  if (yy < 4) {            // paired KV job
    pair = 1;
    c0 = yy * 64;
    b0 = c0;               // K panel rows
    b64 = 256 + c0;        // V panel rows
    cbias0 = c0;           // K bias: idx = cbias0 + lc   (lc < 64)
    cbias64 = 192 + c0;    // V bias: idx = cbias64 + lc  (lc >= 64) = 256+c0+(lc-64)
    Cd = isNP ? KVp : KVa;
  } else {                 // Qeff job
    pair = 0;
    int j = yy - 4;        // NP: 0,1 -> Qe0; 2,3 -> Qe1.  NA: 0,1 -> Qe2
    b0 = 512 + j * 128;
    b64 = b0 + 64;
    qcol0 = (j & 1) * 128;
    cbias0 = 512 + j * 128;
    cbias64 = cbias0;
    Cd = isNP ? (j < 2 ? Qe0 : Qe1) : Qe2;
  }

  const int tid = threadIdx.x;
  const int ln = tid & 63, wv = tid >> 6;
  const int quad = ln >> 4, lr = ln & 15;
  const int wr = wv >> 1, wc = wv & 1;  // 2x2 wave grid over 128x128

  f32x4 acc[4][4];
#pragma unroll
  for (int m = 0; m < 4; m++)
#pragma unroll
    for (int n = 0; n < 4; n++) acc[m][n] = (f32x4){0.f, 0.f, 0.f, 0.f};

  // staging chunk map: thread t stages 16B at LDS ushort t*8 -> local row t>>2, seg t&3
  const int r0 = tid >> 2, seg = tid & 3;
  int ar0 = row0 + r0;      if (ar0 >= M) ar0 = M - 1;  // clamp; guarded at store
  int ar1 = row0 + 64 + r0; if (ar1 >= M) ar1 = M - 1;
  const ushort* gA0 = A + ((size_t)ar0 * 256 + seg * 8);
  const ushort* gA1 = A + ((size_t)ar1 * 256 + seg * 8);
  const ushort* gB0 = B + ((size_t)(b0 + r0) * 256 + seg * 8);
  const ushort* gB1 = B + ((size_t)(b64 + r0) * 256 + seg * 8);
  const int lbase = (tid & 192) * 8;  // wave-uniform LDS ushort offset

  auto stage = [&](int kb, int buf) {
    gload16(gA0 + kb * 32, As[buf] + lbase);
    gload16(gA1 + kb * 32, As[buf] + 2048 + lbase);
    gload16(gB0 + kb * 32, Bs[buf] + lbase);
    gload16(gB1 + kb * 32, Bs[buf] + 2048 + lbase);
  };

  stage(0, 0);
  stage(1, 1);
  asm volatile("s_waitcnt vmcnt(4)" ::: "memory");  // drain tile-0 loads only
  __builtin_amdgcn_s_barrier();
  __builtin_amdgcn_sched_barrier(0);
#pragma unroll
  for (int kb = 0; kb < 8; kb++) {
    const int cur_ = kb % 3;
    if (kb < 6) stage(kb + 2, (kb + 2) % 3);
    bf16x8 af[4], bfr[4];
#pragma unroll
    for (int m = 0; m < 4; m++)
      af[m] = *(const bf16x8*)&As[cur_][(wr * 64 + m * 16 + lr) * 32 + quad * 8];
#pragma unroll
    for (int n = 0; n < 4; n++)
      bfr[n] = *(const bf16x8*)&Bs[cur_][(wc * 64 + n * 16 + lr) * 32 + quad * 8];
    // swapped operands: lane = (row: m*16+lr, cols: n*16+quad*4+r)
#pragma unroll
    for (int m = 0; m < 4; m++)
#pragma unroll
      for (int n = 0; n < 4; n++)
        acc[m][n] = __builtin_amdgcn_mfma_f32_16x16x32_bf16(bfr[n], af[m], acc[m][n], 0, 0, 0);
    if (kb < 7) {
      if (kb < 6) asm volatile("s_waitcnt vmcnt(4)" ::: "memory");  // keep newest batch in flight
      else        asm volatile("s_waitcnt vmcnt(0)" ::: "memory");
      __builtin_amdgcn_s_barrier();
      __builtin_amdgcn_sched_barrier(0);
    }
  }

#pragma unroll
  for (int m = 0; m < 4; m++) {
    int row = row0 + wr * 64 + m * 16 + lr;
    if (row >= M) continue;
#pragma unroll
    for (int n = 0; n < 4; n++) {
      int lc = wc * 64 + n * 16 + quad * 4;  // local col, 4-aligned
      int bidx = ((lc < 64) ? cbias0 : cbias64) + lc;
      float4 bv = *(const float4*)(gbias + bidx);
      ushort4 o;
      o.x = f2b(acc[m][n][0] + bv.x);
      o.y = f2b(acc[m][n][1] + bv.y);
      o.z = f2b(acc[m][n][2] + bv.z);
      o.w = f2b(acc[m][n][3] + bv.w);
      size_t cidx;
      if (pair) {
        int dcol = c0 + (lc & 63);  // K or V dim base (4-aligned)
        cidx = (size_t)row * 512 + (size_t)(dcol >> 2) * 8 + ((lc < 64) ? 0 : 4);
      } else {
        cidx = (size_t)row * 256 + qcol0 + lc;
      }
      *(ushort4*)(Cd + cidx) = o;  // 8B-aligned
    }
  }
}

// out = alpha*(A0@B0^T [+A1@B1^T] + ab) + (1-alpha)*h   (A,B internal bf16)
// 2-D grid. Operand-swapped MFMA -> float4/ushort4 epilogue.
// job y<2 -> author (N=256, 1 group); y>=2 -> paper (2 groups)
__global__ __launch_bounds__(256) void out_gemm2(const ushort* __restrict__ Aa,
                                                 const ushort* __restrict__ Ba_,
                                                 const ushort* __restrict__ Ap0,
                                                 const ushort* __restrict__ Bp0,
                                                 const ushort* __restrict__ Ap1,
                                                 const ushort* __restrict__ Bp1,
                                                 const void* __restrict__ ab,
                                                 const void* __restrict__ h_a,
                                                 const void* __restrict__ h_p,
                                                 const void* __restrict__ skipv,
                                                 void* __restrict__ out,
                                                 const void* __restrict__ rpri) {
  const int y = blockIdx.y;
  const int isA = (y < 2);
  const int M = isA ? NA : NP;
  const int row0 = blockIdx.x * 128;
  if (row0 >= M) return;
  const ushort* A0 = isA ? Aa : Ap0;
  const ushort* B0 = isA ? Ba_ : Bp0;
  const ushort* A1 = isA ? nullptr : Ap1;
  const ushort* B1 = isA ? nullptr : Bp1;
  const int ab_off = isA ? 0 : 256;
  const void* h = isA ? h_a : h_p;
  const int skipidx = isA ? 0 : 1;
  const size_t out_off = isA ? 0 : (size_t)NA * DD;
  const int col0 = (isA ? y : (y - 2)) * 128;

  const int isbf = get_isbf(rpri);
  __shared__ __align__(16) ushort As[2][4096];
  __shared__ __align__(16) ushort Bs[2][4096];
  const int tid = threadIdx.x;
  const int ln = tid & 63, wv = tid >> 6;
  const int quad = ln >> 4, lr = ln & 15;
  const int wr = wv >> 1, wc = wv & 1;

  f32x4 acc[4][4];
#pragma unroll
  for (int m = 0; m < 4; m++)
#pragma unroll
    for (int n = 0; n < 4; n++) acc[m][n] = (f32x4){0.f, 0.f, 0.f, 0.f};

  const int r0 = tid >> 2, seg = tid & 3;
  const int r1 = 64 + r0;
  int ar0 = row0 + r0; if (ar0 >= M) ar0 = M - 1;
  int ar1 = row0 + r1; if (ar1 >= M) ar1 = M - 1;
  const int lbase = (tid & 192) * 8;

  const int nsteps = (A1 != nullptr) ? 16 : 8;
  auto stage = [&](int s, int buf) {
    int g = s >> 3, kb = s & 7;
    const ushort* A = g ? A1 : A0;
    const ushort* B = g ? B1 : B0;
    gload16(A + (size_t)ar0 * 256 + seg * 8 + kb * 32, As[buf] + lbase);
    gload16(A + (size_t)ar1 * 256 + seg * 8 + kb * 32, As[buf] + 2048 + lbase);
    gload16(B + (size_t)(col0 + r0) * 256 + seg * 8 + kb * 32, Bs[buf] + lbase);
    gload16(B + (size_t)(col0 + r1) * 256 + seg * 8 + kb * 32, Bs[buf] + 2048 + lbase);
  };

  stage(0, 0);
  __syncthreads();
  for (int s = 0; s < nsteps; s++) {
    const int cur_ = s & 1;
    if (s + 1 < nsteps) stage(s + 1, cur_ ^ 1);
    bf16x8 af[4], bfr[4];
#pragma unroll
    for (int m = 0; m < 4; m++)
      af[m] = *(const bf16x8*)&As[cur_][(wr * 64 + m * 16 + lr) * 32 + quad * 8];
#pragma unroll
    for (int n = 0; n < 4; n++)
      bfr[n] = *(const bf16x8*)&Bs[cur_][(wc * 64 + n * 16 + lr) * 32 + quad * 8];
#pragma unroll
    for (int m = 0; m < 4; m++)
#pragma unroll
      for (int n = 0; n < 4; n++)
        acc[m][n] = __builtin_amdgcn_mfma_f32_16x16x32_bf16(bfr[n], af[m], acc[m][n], 0, 0, 0);
    __syncthreads();
  }

  float alpha = 1.f / (1.f + __expf(-ldf(skipv, skipidx, isbf)));
  float beta = 1.f - alpha;
#pragma unroll
  for (int m = 0; m < 4; m++) {
    int row = row0 + wr * 64 + m * 16 + lr;
    if (row >= M) continue;
#pragma unroll
    for (int n = 0; n < 4; n++) {
      int col = col0 + wc * 64 + n * 16 + quad * 4;  // 4-aligned
      size_t base = (size_t)row * 256 + col;
      float t0 = acc[m][n][0] + ldf(ab, ab_off + col + 0, isbf);
      float t1 = acc[m][n][1] + ldf(ab, ab_off + col + 1, isbf);
      float t2 = acc[m][n][2] + ldf(ab, ab_off + col + 2, isbf);
      float t3 = acc[m][n][3] + ldf(ab, ab_off + col + 3, isbf);
      if (isbf) {
        ushort4 hu = *(const ushort4*)((const ushort*)h + base);
        ushort4 o;
        o.x = f2b(alpha * t0 + beta * b2f(hu.x));
        o.y = f2b(alpha * t1 + beta * b2f(hu.y));
        o.z = f2b(alpha * t2 + beta * b2f(hu.z));
        o.w = f2b(alpha * t3 + beta * b2f(hu.w));
        *(ushort4*)((ushort*)out + out_off + base) = o;
      } else {
        float4 hf = *(const float4*)((const float*)h + base);
        float4 o;
        o.x = alpha * t0 + beta * hf.x;
        o.y = alpha * t1 + beta * hf.y;
        o.z = alpha * t2 + beta * hf.z;
        o.w = alpha * t3 + beta * hf.w;
        *(float4*)((float*)out + out_off + base) = o;
      }
    }
  }
}

// ---------------- CSR scan kernels ----------------
__global__ __launch_bounds__(256) void reduce_cnt(const int* __restrict__ cnt,
                                                  int* __restrict__ bsum) {
  __shared__ int red[256];
  int t = threadIdx.x;
  int base = blockIdx.x * 2048 + t * 8;
  int s = 0;
#pragma unroll
  for (int j = 0; j < 8; j++) s += (base + j < NTOT) ? cnt[base + j] : 0;
  red[t] = s;
  __syncthreads();
  for (int o = 128; o > 0; o >>= 1) {
    if (t < o) red[t] += red[t + o];
    __syncthreads();
  }
  if (t == 0) bsum[blockIdx.x] = red[0];
}

__global__ __launch_bounds__(64) void scan_top(const int* __restrict__ bsum,
                                               int* __restrict__ ebase) {
  __shared__ int ts[64];
  int t = threadIdx.x;
  int v = (t < NBLK) ? bsum[t] : 0;
  ts[t] = v;
  __syncthreads();
  for (int o = 1; o < 64; o <<= 1) {
    int x = (t >= o) ? ts[t - o] : 0;
    __syncthreads();
    ts[t] += x;
    __syncthreads();
  }
  if (t < NBLK) ebase[t] = ts[t] - v;  // exclusive
}

__global__ __launch_bounds__(256) void scan_final(const int* __restrict__ cnt,
                                                  const int* __restrict__ ebase,
                                                  int* __restrict__ offs,
                                                  int* __restrict__ cur) {
  __shared__ int ts[256];
  int t = threadIdx.x;
  int base = blockIdx.x * 2048 + t * 8;
  int v[8];
  int s = 0;
#pragma unroll
  for (int j = 0; j < 8; j++) {
    int x = (base + j < NTOT) ? cnt[base + j] : 0;
    v[j] = s;
    s += x;
  }
  ts[t] = s;
  __syncthreads();
  for (int o = 1; o < 256; o <<= 1) {
    int x = (t >= o) ? ts[t - o] : 0;
    __syncthreads();
    ts[t] += x;
    __syncthreads();
  }
  int tb = ebase[blockIdx.x] + ts[t] - s;
#pragma unroll
  for (int j = 0; j < 8; j++) {
    int i = base + j;
    if (i < NTOT) {
      int o2 = tb + v[j];
      offs[i] = o2;
      cur[i] = o2;
    }
  }
  if (blockIdx.x == 0 && t == 0) offs[NTOT] = 3 * NE;
}

// ---------------- merged per-dst online-softmax aggregation (one wave per dst) ----------------
// KV layout: row s = 512 ushorts; lane ln's dwordx4 at s*512+ln*8 = {k0..k3, v0..v3}
// Chunked online softmax: 8 edges/iter, unconditional clamped loads (padded slots
// get sc=-1e30 -> exp underflows to exact 0 -> bit-identical); prif folded into q;
// first chunk skips the rescale chain.
__global__ __launch_bounds__(256) void edge_agg_all(ushort* __restrict__ Qe0,
                                                    ushort* __restrict__ Qe1,
                                                    ushort* __restrict__ Qe2,
                                                    const ushort* __restrict__ KVa,
                                                    const ushort* __restrict__ KVp,
                                                    const int* __restrict__ offs,
                                                    const int* __restrict__ csr,
                                                    const void* __restrict__ pri) {
  int isbf = get_isbf(pri);
  int wv = threadIdx.x >> 6;
  int g = blockIdx.x * 4 + wv;
  if (g >= NTOT) return;
  int ln = threadIdx.x & 63;
  int h = ln >> 3;
  int d, pri_off, n_src;
  ushort* Q;
  const ushort* KV;
  if (g < NP) {
    d = g; Q = Qe0; KV = KVa; pri_off = 0; n_src = NA;
  } else if (g < 2 * NP) {
    d = g - NP; Q = Qe1; KV = KVp; pri_off = 8; n_src = NP;
  } else {
    d = g - 2 * NP; Q = Qe2; KV = KVp; pri_off = 16; n_src = NP;
  }
  float prif = ldf(pri, pri_off + h, isbf) * 0.17677669529663687f;  // 1/sqrt(32)
  ushort4 qu = *(const ushort4*)(Q + (size_t)d * 256 + ln * 4);
  float q0 = b2f(qu.x) * prif, q1 = b2f(qu.y) * prif;
  float q2 = b2f(qu.z) * prif, q3 = b2f(qu.w) * prif;
  float m = -1e30f, l = 0.f;
  float a0 = 0.f, a1 = 0.f, a2 = 0.f, a3 = 0.f;
  int e0 = __builtin_amdgcn_readfirstlane(offs[g]);
  int e1 = __builtin_amdgcn_readfirstlane(offs[g + 1]);
  if (e1 > e0 + 4096) e1 = e0 + 4096;  // firewall
  const int elast = e1 - 1;

  for (int e = e0; e < e1; e += 8) {
    int nv = e1 - e;
    nv = (nv > 8) ? 8 : nv;  // wave-uniform
    int4 kv[8];
    float sc[8];
    // unconditional clamped loads: 8-deep memory pipeline, no exec-mask churn
#pragma unroll
    for (int i = 0; i < 8; i++) {
      int idx = e + i;
      idx = (idx > elast) ? elast : idx;
      unsigned s = (unsigned)__builtin_amdgcn_readfirstlane(csr[idx]);  // scalar
      if (s >= (unsigned)n_src) s = 0;  // firewall
      kv[i] = *(const int4*)(KV + (size_t)s * 512 + ln * 8);
    }
    // independent dot + reduce per edge; padded slots -> -1e30
#pragma unroll
    for (int i = 0; i < 8; i++) {
      float p = q0 * b2f_lo(kv[i].x) + q1 * b2f_hi(kv[i].x) +
                q2 * b2f_lo(kv[i].y) + q3 * b2f_hi(kv[i].y);
      p += __shfl_xor(p, 1);
      p += __shfl_xor(p, 2);
      p += __shfl_xor(p, 4);
      sc[i] = (i < nv) ? p : -1e30f;
    }
    // one max-merge + one rescale per chunk (first chunk: l,a zero -> skip)
    float mc = fmaxf(fmaxf(fmaxf(sc[0], sc[1]), fmaxf(sc[2], sc[3])),
                     fmaxf(fmaxf(sc[4], sc[5]), fmaxf(sc[6], sc[7])));
    float mn = fmaxf(m, mc);
    if (e != e0) {
      float scale = __expf(m - mn);
      l *= scale; a0 *= scale; a1 *= scale; a2 *= scale; a3 *= scale;
    }
    // unconditional accumulate: padded wgt = exp(-1e30 - mn) = exact 0
#pragma unroll
    for (int i = 0; i < 8; i++) {
      float wgt = __expf(sc[i] - mn);
      l += wgt;
      a0 += wgt * b2f_lo(kv[i].z);
      a1 += wgt * b2f_hi(kv[i].z);
      a2 += wgt * b2f_lo(kv[i].w);
      a3 += wgt * b2f_hi(kv[i].w);
    }
    m = mn;
  }
  float inv = (l > 0.f) ? 1.f / l : 0.f;
  ushort4 o;
  o.x = f2b(a0 * inv);
  o.y = f2b(a1 * inv);
  o.z = f2b(a2 * inv);
  o.w = f2b(a3 * inv);
  *(ushort4*)(Q + (size_t)d * 256 + ln * 4) = o;  // in-place agg
}

// ---------------- launch ----------------
extern "C" void kernel_launch(void* const* d_in, const int* in_sizes, int n_in,
                              void* d_out, int out_size, void* d_ws, size_t ws_size,
                              hipStream_t stream) {
  (void)in_sizes; (void)n_in; (void)out_size; (void)ws_size;
  const void* h_a = d_in[0];
  const void* h_p = d_in[1];
  const void* k_w = d_in[2];
  const void* k_b = d_in[3];
  const void* q_w = d_in[4];
  const void* q_b = d_in[5];
  const void* v_w = d_in[6];
  const void* v_b = d_in[7];
  const void* a_w = d_in[8];
  const void* a_b = d_in[9];
  const void* ratt = d_in[10];
  const void* rmsg = d_in[11];
  const void* rpri = d_in[12];
  const void* skip = d_in[13];
  const int* src_w = (const int*)d_in[14];
  const int* dst_w = (const int*)d_in[15];
  const int* src_c = (const int*)d_in[16];
  const int* dst_c = (const int*)d_in[17];
  const int* src_b = (const int*)d_in[18];
  const int* dst_b = (const int*)d_in[19];

  char* w = (char*)d_ws;
  size_t ofs = 0;
  auto alloc = [&](size_t bytes) {
    char* p = w + ofs;
    ofs = (ofs + bytes + 255) & ~(size_t)255;
    return p;
  };
  ushort* Bp = (ushort*)alloc((size_t)1024 * 256 * 2);  // [kw1; vw1; qeff e0; qeff e1]
  ushort* Ba = (ushort*)alloc((size_t)768 * 256 * 2);   // [kw0; vw0; qeff e2]
  ushort* aeff = (ushort*)alloc((size_t)3 * 256 * 256 * 2);
  float* gb = (float*)alloc((size_t)7 * 256 * 4);
  int* cnt = (int*)alloc((size_t)NTOT * 4);
  int* offs = (int*)alloc((size_t)(NTOT + 1) * 4);
  int* bsum = (int*)alloc(64 * 4);
  int* ebase = (int*)alloc(64 * 4);
  int* cur = (int*)alloc((size_t)NTOT * 4);
  int* csr = (int*)alloc((size_t)3 * NE * 4);
  ushort* Ha = (ushort*)alloc((size_t)NA * DD * 2);    // bf16 h_author
  ushort* Hp = (ushort*)alloc((size_t)NP * DD * 2);    // bf16 h_paper
  ushort* KVa = (ushort*)alloc((size_t)NA * 512 * 2);  // interleaved K/V, author srcs
  ushort* KVp = (ushort*)alloc((size_t)NP * 512 * 2);  // interleaved K/V, paper srcs
  ushort* Qe0 = (ushort*)alloc((size_t)NP * DD * 2);
  ushort* Qe1 = (ushort*)alloc((size_t)NP * DD * 2);
  ushort* Qe2 = (ushort*)alloc((size_t)NA * DD * 2);
  ushort* agg0 = Qe0;  // in-place edge_agg
  ushort* agg1 = Qe1;
  ushort* agg2 = Qe2;

  hipMemsetAsync(cnt, 0, (size_t)NTOT * 4, stream);

  // phase0: cvt_h || prep || count_edges (all mutually independent)
  phase0<<<CVT_B + PREP_B + CNT_B, 256, 0, stream>>>(
      h_a, h_p, Ha, Hp, q_w, a_w, k_w, v_w, k_b, v_b, q_b, ratt, rmsg,
      Bp, Ba, aeff, gb, dst_w, dst_c, dst_b, cnt, rpri);

  // CSR scan chain
  reduce_cnt<<<NBLK, 256, 0, stream>>>(cnt, bsum);
  scan_top<<<1, 64, 0, stream>>>(bsum, ebase);
  scan_final<<<NBLK, 256, 0, stream>>>(cnt, ebase, offs, cur);

  // projections || scatter (mutually independent)
  proj_scatter<<<PROJ_B + SCAT_B, 256, 0, stream>>>(
      Hp, Ha, Bp, Ba, gb, KVp, KVa, Qe0, Qe1, Qe2,
      src_w, dst_w, src_c, dst_c, src_b, dst_b, cur, csr);

  // merged aggregation: one wave per joint dst bucket
  edge_agg_all<<<(NTOT + 3) / 4, 256, 0, stream>>>(Qe0, Qe1, Qe2, KVa, KVp,
                                                   offs, csr, rpri);

  // merged output GEMM (2-D grid): y<2 author, y>=2 paper
  out_gemm2<<<dim3((NP + 127) / 128, 4), 256, 0, stream>>>(
      agg2, aeff + 131072, agg0, aeff, agg1, aeff + 65536,
      a_b, h_a, h_p, skip, d_out, rpri);
}